// Round 8
// baseline (770.577 us; speedup 1.0000x reference)
//
#include <hip/hip_runtime.h>
#include <hip/hip_bf16.h>

// Problem constants
constexpr int B = 4, N = 2048, M = 2048, H = 512, ITERS = 20;
constexpr int ROWS_TOT = B * (N + M);  // 16384
constexpr float EPS_IN = 1e-5f;
constexpr float LOG2E = 1.4426950408889634f;
constexpr float LN2 = 0.6931471805599453f;

typedef unsigned short ushort_t;
typedef unsigned int uint_t;

__device__ __forceinline__ float fexp2(float x) { return __builtin_amdgcn_exp2f(x); }
__device__ __forceinline__ float flog2(float x) { return __builtin_amdgcn_logf(x); }
__device__ __forceinline__ float blo(uint_t v) { return __uint_as_float(v << 16); }
__device__ __forceinline__ float bhi(uint_t v) { return __uint_as_float(v & 0xffff0000u); }
// round-to-nearest-even f32 -> bf16 (inputs finite)
__device__ __forceinline__ uint_t bf16rn(float f) {
  uint_t x = __float_as_uint(f);
  return (x + 0x7fffu + ((x >> 16) & 1u)) >> 16;
}

// ---------------------------------------------------------------------------
// Kernel 1: projections -> qwT[k][row] (64 x 16384), plus per-row sq norms.
// ---------------------------------------------------------------------------
__global__ __launch_bounds__(256) void proj_kernel(
    const float* __restrict__ x, const float* __restrict__ y,
    const float* __restrict__ Wq, const float* __restrict__ bq,
    float* __restrict__ qwT, float* __restrict__ norms, float* __restrict__ stats) {
  __shared__ float Wl[64][65];
  __shared__ float Xl[32][65];
  __shared__ float T[32][65];
  int t = threadIdx.x;
  int r0 = blockIdx.x * 32;
  const float* src = (r0 < B * N) ? x + (size_t)r0 * H
                                  : y + (size_t)(r0 - B * N) * H;
  if (blockIdx.x == 0 && t < 32) stats[t] = 0.0f;

  int k = t & 63;
  float bias = bq[k];
  float acc[8];
#pragma unroll
  for (int c = 0; c < 8; c++) acc[c] = 0.0f;

  for (int hc = 0; hc < H; hc += 64) {
#pragma unroll
    for (int l = 0; l < 16; l++) {
      int idx = t + l * 256;
      int kk = idx >> 6, hh = idx & 63;
      Wl[kk][hh] = Wq[(size_t)kk * H + hc + hh];
    }
#pragma unroll
    for (int l = 0; l < 8; l++) {
      int idx = t + l * 256;
      int rr = idx >> 6, hh = idx & 63;
      Xl[rr][hh] = src[(size_t)rr * H + hc + hh];
    }
    __syncthreads();
    int rbase = (t >> 6) * 8;
#pragma unroll
    for (int hh = 0; hh < 64; hh++) {
      float w = Wl[k][hh];
#pragma unroll
      for (int c = 0; c < 8; c++) acc[c] = fmaf(Xl[rbase + c][hh], w, acc[c]);
    }
    __syncthreads();
  }
  int rbase = (t >> 6) * 8;
#pragma unroll
  for (int c = 0; c < 8; c++) {
    float v = acc[c] + bias;
    T[rbase + c][k] = v;
    float sq = v * v;
#pragma unroll
    for (int off = 32; off; off >>= 1) sq += __shfl_xor(sq, off, 64);
    if (k == 0) norms[r0 + rbase + c] = sq;
  }
  __syncthreads();
#pragma unroll
  for (int p = 0; p < 8; p++) {
    int idx = p * 256 + t;
    int kk = idx >> 5, rr = idx & 31;
    qwT[(size_t)kk * ROWS_TOT + r0 + rr] = T[rr][kk];
  }
}

// ---------------------------------------------------------------------------
// Kernel 2: e[b,n,m] = exp(-dist) -> bf16 in d_out, plus per-batch
// sum/sumsq/max.  128x64 tile (2048 blocks -> 8 blocks/CU), 2x32 k-stages,
// 8x4 microtile.  LDS 24 KB.
// ---------------------------------------------------------------------------
__global__ __launch_bounds__(256) void dist_kernel(
    const float* __restrict__ qwT, const float* __restrict__ norms,
    ushort_t* __restrict__ e, float* __restrict__ stats) {
  __shared__ float xtT[32][128];
  __shared__ float ytT[32][64];
  int t = threadIdx.x;
  int b = blockIdx.z;
  int n0 = blockIdx.x * 128, m0 = blockIdx.y * 64;
  int xbase = b * N + n0;
  int ybase = B * N + b * M + m0;

  int w = t >> 6, lane = t & 63;
  int ri = (w >> 1) * 64 + (lane >> 3) * 8;  // local x-row base (0..120)
  int ci = (w & 1) * 32 + (lane & 7) * 4;    // local y-row base (0..60)

  float acc[8][4] = {};
  for (int kc = 0; kc < 64; kc += 32) {
    if (kc) __syncthreads();
#pragma unroll
    for (int p = 0; p < 4; p++) {
      int idx = p * 256 + t;
      int kk = idx >> 5, seg = (idx & 31) * 4;
      *(float4*)&xtT[kk][seg] =
          *(const float4*)(qwT + (size_t)(kc + kk) * ROWS_TOT + xbase + seg);
    }
#pragma unroll
    for (int p = 0; p < 2; p++) {
      int idx = p * 256 + t;
      int kk = idx >> 4, seg = (idx & 15) * 4;
      *(float4*)&ytT[kk][seg] =
          *(const float4*)(qwT + (size_t)(kc + kk) * ROWS_TOT + ybase + seg);
    }
    __syncthreads();
#pragma unroll 4
    for (int kk = 0; kk < 32; kk++) {
      float4 a0 = *(const float4*)&xtT[kk][ri];
      float4 a1 = *(const float4*)&xtT[kk][ri + 4];
      float4 b0 = *(const float4*)&ytT[kk][ci];
      float av[8] = {a0.x, a0.y, a0.z, a0.w, a1.x, a1.y, a1.z, a1.w};
      float bv[4] = {b0.x, b0.y, b0.z, b0.w};
#pragma unroll
      for (int i = 0; i < 8; i++)
#pragma unroll
        for (int j = 0; j < 4; j++) acc[i][j] = fmaf(av[i], bv[j], acc[i][j]);
    }
  }

  float4 xnA = *(const float4*)(norms + b * N + n0 + ri);
  float4 xnB = *(const float4*)(norms + b * N + n0 + ri + 4);
  float4 ynA = *(const float4*)(norms + B * N + b * M + m0 + ci);
  float xv[8] = {xnA.x, xnA.y, xnA.z, xnA.w, xnB.x, xnB.y, xnB.z, xnB.w};
  float yv[4] = {ynA.x, ynA.y, ynA.z, ynA.w};

  float lsum = 0.0f, lsq = 0.0f, lmax = 0.0f;
#pragma unroll
  for (int i = 0; i < 8; i++) {
    float o[4];
#pragma unroll
    for (int j = 0; j < 4; j++) {
      float d = xv[i] + yv[j] - 2.0f * acc[i][j];
      float v = __expf(-d);
      o[j] = v;
      lsum += v;
      lsq += v * v;
      lmax = fmaxf(lmax, v);
    }
    uint2 pk;
    pk.x = bf16rn(o[0]) | (bf16rn(o[1]) << 16);
    pk.y = bf16rn(o[2]) | (bf16rn(o[3]) << 16);
    size_t row = (size_t)(b * N + n0 + ri + i);
    *(uint2*)(e + row * M + m0 + ci) = pk;
  }

#pragma unroll
  for (int off = 32; off; off >>= 1) {
    lsum += __shfl_xor(lsum, off, 64);
    lsq += __shfl_xor(lsq, off, 64);
    lmax = fmaxf(lmax, __shfl_xor(lmax, off, 64));
  }
  __syncthreads();
  float* scr = (float*)xtT;
  if (lane == 0) { scr[w] = lsum; scr[4 + w] = lsq; scr[8 + w] = lmax; }
  __syncthreads();
  if (t == 0) {
    float ssum = scr[0] + scr[1] + scr[2] + scr[3];
    float ssq = scr[4] + scr[5] + scr[6] + scr[7];
    float smax = fmaxf(fmaxf(scr[8], scr[9]), fmaxf(scr[10], scr[11]));
    atomicAdd(&stats[b * 4 + 0], ssum);
    atomicAdd(&stats[b * 4 + 1], ssq);
    atomicMax((unsigned int*)&stats[b * 4 + 2], __float_as_uint(smax));
  }
}

// ---------------------------------------------------------------------------
// Kernel 3: per-batch params.
// params[b*8] = {sL = s*log2e, c0L = (t-2KK)*log2e, KK, enk=e^-KK, ekk=e^KK}
// ---------------------------------------------------------------------------
__global__ void params_kernel(const float* __restrict__ stats,
                              const float* __restrict__ in_w,
                              const float* __restrict__ in_b,
                              float* __restrict__ params) {
  int b = threadIdx.x;
  if (b >= B) return;
  float NMf = (float)N * (float)M;
  float mean = stats[b * 4 + 0] / NMf;
  float var = stats[b * 4 + 1] / NMf - mean * mean;
  var = fmaxf(var, 0.0f);
  float stdv = sqrtf(var + EPS_IN);
  float s = in_w[0] / stdv;
  float t = in_b[0] - mean * s;
  float emax = __uint_as_float(((const unsigned int*)stats)[b * 4 + 2]);
  float Amax = fmaxf(fmaf(s, emax, t), t);
  float KK = fmaxf(Amax - 60.0f, 0.0f);
  params[b * 8 + 0] = s * LOG2E;
  params[b * 8 + 1] = (t - 2.0f * KK) * LOG2E;
  params[b * 8 + 2] = KK;
  params[b * 8 + 3] = __expf(-KK);
  params[b * 8 + 4] = __expf(KK);
}

// Zero all three colsum rotation buffers (24576 floats).
__global__ void csinit_kernel(float* __restrict__ csb) {
  int g = blockIdx.x * 256 + threadIdx.x;
  *(float4*)(csb + g * 4) = float4{0.f, 0.f, 0.f, 0.f};
}

// ---------------------------------------------------------------------------
// Kernel 5: fused sinkhorn iteration, 1 row per WAVE (2048 blocks -> 8/CU).
// e-loads issued before the prologue so their latency hides under it.
// LDS 16 KB: colA/colB alias C2a/C2b (extra barrier after PASS2).
// Epilogue atomics wave-coalesced (round-7-proven).
// ---------------------------------------------------------------------------
#define PASS1(uu, off)                                   \
  {                                                      \
    float4 ca = *(const float4*)&C2a[(off) + ln4];       \
    float4 cb = *(const float4*)&C2b[(off) + ln4];       \
    s0 += fexp2(fmaf(blo(uu.x), sL, ca.x));              \
    s1 += fexp2(fmaf(bhi(uu.x), sL, ca.y));              \
    s2 += fexp2(fmaf(blo(uu.y), sL, ca.z));              \
    s3 += fexp2(fmaf(bhi(uu.y), sL, ca.w));              \
    s0 += fexp2(fmaf(blo(uu.z), sL, cb.x));              \
    s1 += fexp2(fmaf(bhi(uu.z), sL, cb.y));              \
    s2 += fexp2(fmaf(blo(uu.w), sL, cb.z));              \
    s3 += fexp2(fmaf(bhi(uu.w), sL, cb.w));              \
  }

#define PASS2(uu, off, AA, BB)                           \
  {                                                      \
    float4 ca = *(const float4*)&C2a[(off) + ln4];       \
    float4 cb = *(const float4*)&C2b[(off) + ln4];       \
    AA.x = fexp2(fmaf(blo(uu.x), sL, ca.x + gL));        \
    AA.y = fexp2(fmaf(bhi(uu.x), sL, ca.y + gL));        \
    AA.z = fexp2(fmaf(blo(uu.y), sL, ca.z + gL));        \
    AA.w = fexp2(fmaf(bhi(uu.y), sL, ca.w + gL));        \
    BB.x = fexp2(fmaf(blo(uu.z), sL, cb.x + gL));        \
    BB.y = fexp2(fmaf(bhi(uu.z), sL, cb.y + gL));        \
    BB.z = fexp2(fmaf(blo(uu.w), sL, cb.z + gL));        \
    BB.w = fexp2(fmaf(bhi(uu.w), sL, cb.w + gL));        \
  }

__global__ __launch_bounds__(256) void sink_pass(
    const ushort_t* __restrict__ e, const float* __restrict__ params,
    const float* __restrict__ cs_cur, float* __restrict__ cs_nxt,
    float* __restrict__ cs_zz, float* __restrict__ R) {
  __shared__ __align__(16) float smem[4096];  // 16 KB
  float* C2a = smem;         // [1024]
  float* C2b = smem + 1024;  // [1024]
  float* Ds = smem + 2048;   // [2048]
  float* colA = smem;        // alias of C2a (used after PASS2 barrier)
  float* colB = smem + 1024; // alias of C2b
  int t = threadIdx.x;
  int b = blockIdx.y, blk = blockIdx.x;  // blk 0..511
  int w = t >> 6, lane = t & 63;
  int ln4 = lane * 4;
  const float* pr = params + b * 8;
  float sL = pr[0], c0L = pr[1], KK = pr[2], enk = pr[3], ekk = pr[4];

  // issue this wave's e-row loads FIRST (latency hidden under prologue)
  int r = blk * 4 + w;
  const ushort_t* ep = e + (size_t)(b * N + r) * M + lane * 8;
  uint4 u0 = *(const uint4*)(ep);
  uint4 u1 = *(const uint4*)(ep + 512);
  uint4 u2 = *(const uint4*)(ep + 1024);
  uint4 u3 = *(const uint4*)(ep + 1536);

  if (blk == 0) {  // coalesced zero of next iteration's accumulator
#pragma unroll
    for (int k = 0; k < 2; k++)
      *(float4*)(cs_zz + b * M + (k * 256 + t) * 4) = float4{0.f, 0.f, 0.f, 0.f};
  }
  {  // prologue: thread t owns columns [t*8, t*8+8)
    float4 v0 = *(const float4*)(cs_cur + b * M + t * 8);
    float4 v1 = *(const float4*)(cs_cur + b * M + t * 8 + 4);
    v0.x += enk; v0.y += enk; v0.z += enk; v0.w += enk;
    v1.x += enk; v1.y += enk; v1.z += enk; v1.w += enk;
    float4 ca, cb;
    ca.x = c0L - flog2(v0.x); ca.y = c0L - flog2(v0.y);
    ca.z = c0L - flog2(v0.z); ca.w = c0L - flog2(v0.w);
    cb.x = c0L - flog2(v1.x); cb.y = c0L - flog2(v1.y);
    cb.z = c0L - flog2(v1.z); cb.w = c0L - flog2(v1.w);
    *(float4*)&C2a[w * 256 + ln4] = ca;
    *(float4*)&C2b[w * 256 + ln4] = cb;
    float4 d0 = {ekk * v0.x, ekk * v0.y, ekk * v0.z, ekk * v0.w};
    float4 d1 = {ekk * v1.x, ekk * v1.y, ekk * v1.z, ekk * v1.w};
    *(float4*)&Ds[t * 8] = d0;  // Ds is plain column-indexed
    *(float4*)&Ds[t * 8 + 4] = d1;
  }
  __syncthreads();

  float4 accA0, accA1, accA2, accA3, accB0, accB1, accB2, accB3;

  float s0 = 0, s1 = 0, s2 = 0, s3 = 0;
  PASS1(u0, 0)
  PASS1(u1, 256)
  PASS1(u2, 512)
  PASS1(u3, 768)
  float sum = (s0 + s1) + (s2 + s3);
#pragma unroll
  for (int off = 32; off; off >>= 1) sum += __shfl_xor(sum, off, 64);
  float sumtot = sum + enk;
  float ls = flog2(sumtot);
  if (lane == 0) R[b * N + r] = KK + LN2 * ls;
  float gL = -KK * LOG2E - ls;  // log2(g), g = enk/sumtot

  PASS2(u0, 0, accA0, accB0)
  PASS2(u1, 256, accA1, accB1)
  PASS2(u2, 512, accA2, accB2)
  PASS2(u3, 768, accA3, accB3)

  __syncthreads();  // everyone done reading C2 -> colA/colB may overwrite

  // combine the 4 waves' column partials in LDS (permuted layout)
  for (int ww = 0; ww < 4; ww++) {
    if (w == ww) {
      if (ww == 0) {
        *(float4*)&colA[ln4] = accA0;
        *(float4*)&colA[256 + ln4] = accA1;
        *(float4*)&colA[512 + ln4] = accA2;
        *(float4*)&colA[768 + ln4] = accA3;
        *(float4*)&colB[ln4] = accB0;
        *(float4*)&colB[256 + ln4] = accB1;
        *(float4*)&colB[512 + ln4] = accB2;
        *(float4*)&colB[768 + ln4] = accB3;
      } else {
        float4 q;
        q = *(float4*)&colA[ln4];
        q.x += accA0.x; q.y += accA0.y; q.z += accA0.z; q.w += accA0.w;
        *(float4*)&colA[ln4] = q;
        q = *(float4*)&colA[256 + ln4];
        q.x += accA1.x; q.y += accA1.y; q.z += accA1.z; q.w += accA1.w;
        *(float4*)&colA[256 + ln4] = q;
        q = *(float4*)&colA[512 + ln4];
        q.x += accA2.x; q.y += accA2.y; q.z += accA2.z; q.w += accA2.w;
        *(float4*)&colA[512 + ln4] = q;
        q = *(float4*)&colA[768 + ln4];
        q.x += accA3.x; q.y += accA3.y; q.z += accA3.z; q.w += accA3.w;
        *(float4*)&colA[768 + ln4] = q;
        q = *(float4*)&colB[ln4];
        q.x += accB0.x; q.y += accB0.y; q.z += accB0.z; q.w += accB0.w;
        *(float4*)&colB[ln4] = q;
        q = *(float4*)&colB[256 + ln4];
        q.x += accB1.x; q.y += accB1.y; q.z += accB1.z; q.w += accB1.w;
        *(float4*)&colB[256 + ln4] = q;
        q = *(float4*)&colB[512 + ln4];
        q.x += accB2.x; q.y += accB2.y; q.z += accB2.z; q.w += accB2.w;
        *(float4*)&colB[512 + ln4] = q;
        q = *(float4*)&colB[768 + ln4];
        q.x += accB3.x; q.y += accB3.y; q.z += accB3.z; q.w += accB3.w;
        *(float4*)&colB[768 + ln4] = q;
      }
    }
    __syncthreads();
  }
  {  // epilogue: WAVE-COALESCED atomics; thread t owns columns {k*256+t}.
    int q = t & 7;
    const float* srcb = (q < 4) ? colA : colB;
    int qq = q & 3;
#pragma unroll
    for (int k = 0; k < 8; k++) {
      int j = k * 256 + t;
      int idx = (j >> 9) * 256 + ((j >> 3) & 63) * 4 + qq;
      atomicAdd(&cs_nxt[b * M + j], srcb[idx] * Ds[j]);
    }
  }
}

// ---------------------------------------------------------------------------
// Kernel 7: aw[i] = exp2(max_j fma(e,sL,C2L_j) + (KK - R_i)*log2e).
// ---------------------------------------------------------------------------
__global__ __launch_bounds__(256) void awmax_kernel(
    const ushort_t* __restrict__ e, const float* __restrict__ params,
    const float* __restrict__ cs_fin, const float* __restrict__ R,
    float* __restrict__ aw) {
  __shared__ __align__(16) float C2a[1024], C2b[1024];
  int t = threadIdx.x;
  int b = blockIdx.y, blk = blockIdx.x;
  const float* pr = params + b * 8;
  float sL = pr[0], c0L = pr[1], KK = pr[2], enk = pr[3];
  {
    float4 v0 = *(const float4*)(cs_fin + b * M + t * 8);
    float4 v1 = *(const float4*)(cs_fin + b * M + t * 8 + 4);
    float4 ca, cb;
    ca.x = c0L - flog2(v0.x + enk); ca.y = c0L - flog2(v0.y + enk);
    ca.z = c0L - flog2(v0.z + enk); ca.w = c0L - flog2(v0.w + enk);
    cb.x = c0L - flog2(v1.x + enk); cb.y = c0L - flog2(v1.y + enk);
    cb.z = c0L - flog2(v1.z + enk); cb.w = c0L - flog2(v1.w + enk);
    int it = t >> 6, ln = t & 63;
    *(float4*)&C2a[it * 256 + ln * 4] = ca;
    *(float4*)&C2b[it * 256 + ln * 4] = cb;
  }
  __syncthreads();

  int w = t >> 6, lane = t & 63;
  int ln4 = lane * 4;
  int r0 = blk * 16 + w * 4;
  const ushort_t* erow = e + (size_t)(b * N + r0) * M;
#pragma unroll
  for (int rr = 0; rr < 4; rr++) {
    float mx = -3.4e38f;
#pragma unroll
    for (int it = 0; it < 4; it++) {
      uint4 u = *(const uint4*)(erow + (size_t)rr * M + it * 512 + lane * 8);
      float4 ca = *(const float4*)&C2a[it * 256 + ln4];
      float4 cb = *(const float4*)&C2b[it * 256 + ln4];
      mx = fmaxf(mx, fmaf(blo(u.x), sL, ca.x));
      mx = fmaxf(mx, fmaf(bhi(u.x), sL, ca.y));
      mx = fmaxf(mx, fmaf(blo(u.y), sL, ca.z));
      mx = fmaxf(mx, fmaf(bhi(u.y), sL, ca.w));
      mx = fmaxf(mx, fmaf(blo(u.z), sL, cb.x));
      mx = fmaxf(mx, fmaf(bhi(u.z), sL, cb.y));
      mx = fmaxf(mx, fmaf(blo(u.w), sL, cb.z));
      mx = fmaxf(mx, fmaf(bhi(u.w), sL, cb.w));
    }
#pragma unroll
    for (int off = 32; off; off >>= 1) mx = fmaxf(mx, __shfl_xor(mx, off, 64));
    if (lane == 0) {
      float Rr = R[b * N + r0 + rr];
      aw[b * N + r0 + rr] = fexp2(mx + (KK - Rr) * LOG2E);
    }
  }
}

// ---------------------------------------------------------------------------
// Kernel 8: out[b,n,m] = aw[b,n] * aw[b,m], float4 stores.
// ---------------------------------------------------------------------------
__global__ __launch_bounds__(256) void outer_kernel(const float* __restrict__ aw,
                                                    float* __restrict__ out) {
  size_t idx = (size_t)blockIdx.x * 256 + threadIdx.x;
  int b = (int)(idx >> 20);
  size_t rem = idx & ((1u << 20) - 1);
  int n = (int)(rem >> 9);
  int m4 = (int)(rem & 511) << 2;
  float a = aw[b * N + n];
  float4 wv = *(const float4*)(aw + b * N + m4);
  float4 o = {a * wv.x, a * wv.y, a * wv.z, a * wv.w};
  *(float4*)(out + (idx << 2)) = o;
}

// ---------------------------------------------------------------------------
extern "C" void kernel_launch(void* const* d_in, const int* in_sizes, int n_in,
                              void* d_out, int out_size, void* d_ws, size_t ws_size,
                              hipStream_t stream) {
  const float* x = (const float*)d_in[0];
  const float* y = (const float*)d_in[1];
  const float* Wq = (const float*)d_in[2];
  const float* bq = (const float*)d_in[3];
  const float* in_w = (const float*)d_in[4];
  const float* in_b = (const float*)d_in[5];
  ushort_t* e = (ushort_t*)d_out;  // 33.5 MB bf16 scratch; overwritten by outer

  float* ws = (float*)d_ws;
  float* qwT = ws;                   // 1048576
  float* norms = ws + 1048576;       // 16384
  float* R = norms + 16384;          // 8192
  float* csb0 = R + 8192;            // 8192
  float* csb1 = csb0 + 8192;         // 8192
  float* csb2 = csb1 + 8192;         // 8192
  float* aw = csb2 + 8192;           // 8192
  float* stats = aw + 8192;          // 32
  float* params = stats + 32;        // 32
  float* csb[3] = {csb0, csb1, csb2};

  proj_kernel<<<512, 256, 0, stream>>>(x, y, Wq, bq, qwT, norms, stats);
  dist_kernel<<<dim3(16, 32, B), 256, 0, stream>>>(qwT, norms, e, stats);
  params_kernel<<<1, 64, 0, stream>>>(stats, in_w, in_b, params);
  csinit_kernel<<<24, 256, 0, stream>>>(csb0);  // zeroes csb0..csb2

  for (int it = 0; it < ITERS; it++) {
    sink_pass<<<dim3(512, B), 256, 0, stream>>>(
        e, params, csb[it % 3], csb[(it + 1) % 3], csb[(it + 2) % 3], R);
  }
  awmax_kernel<<<dim3(128, B), 256, 0, stream>>>(e, params, csb[ITERS % 3], R, aw);
  outer_kernel<<<16384, 256, 0, stream>>>(aw, (float*)d_out);
}

// Round 9
// 418.743 us; speedup vs baseline: 1.8402x; 1.8402x over previous
//
#include <hip/hip_runtime.h>
#include <hip/hip_bf16.h>

// Problem constants
constexpr int B = 4, N = 2048, M = 2048, H = 512, ITERS = 20;
constexpr int ROWS_TOT = B * (N + M);  // 16384
constexpr float EPS_IN = 1e-5f;
constexpr float LOG2E = 1.4426950408889634f;
constexpr float LN2 = 0.6931471805599453f;

typedef unsigned short ushort_t;
typedef unsigned int uint_t;

__device__ __forceinline__ float fexp2(float x) { return __builtin_amdgcn_exp2f(x); }
__device__ __forceinline__ float flog2(float x) { return __builtin_amdgcn_logf(x); }
__device__ __forceinline__ float blo(uint_t v) { return __uint_as_float(v << 16); }
__device__ __forceinline__ float bhi(uint_t v) { return __uint_as_float(v & 0xffff0000u); }
// round-to-nearest-even f32 -> bf16 (inputs finite)
__device__ __forceinline__ uint_t bf16rn(float f) {
  uint_t x = __float_as_uint(f);
  return (x + 0x7fffu + ((x >> 16) & 1u)) >> 16;
}

// ---------------------------------------------------------------------------
// Kernel 1: projections -> qwT[k][row] (64 x 16384), plus per-row sq norms.
// ---------------------------------------------------------------------------
__global__ __launch_bounds__(256) void proj_kernel(
    const float* __restrict__ x, const float* __restrict__ y,
    const float* __restrict__ Wq, const float* __restrict__ bq,
    float* __restrict__ qwT, float* __restrict__ norms, float* __restrict__ stats) {
  __shared__ float Wl[64][65];
  __shared__ float Xl[32][65];
  __shared__ float T[32][65];
  int t = threadIdx.x;
  int r0 = blockIdx.x * 32;
  const float* src = (r0 < B * N) ? x + (size_t)r0 * H
                                  : y + (size_t)(r0 - B * N) * H;
  if (blockIdx.x == 0 && t < 32) stats[t] = 0.0f;

  int k = t & 63;
  float bias = bq[k];
  float acc[8];
#pragma unroll
  for (int c = 0; c < 8; c++) acc[c] = 0.0f;

  for (int hc = 0; hc < H; hc += 64) {
#pragma unroll
    for (int l = 0; l < 16; l++) {
      int idx = t + l * 256;
      int kk = idx >> 6, hh = idx & 63;
      Wl[kk][hh] = Wq[(size_t)kk * H + hc + hh];
    }
#pragma unroll
    for (int l = 0; l < 8; l++) {
      int idx = t + l * 256;
      int rr = idx >> 6, hh = idx & 63;
      Xl[rr][hh] = src[(size_t)rr * H + hc + hh];
    }
    __syncthreads();
    int rbase = (t >> 6) * 8;
#pragma unroll
    for (int hh = 0; hh < 64; hh++) {
      float w = Wl[k][hh];
#pragma unroll
      for (int c = 0; c < 8; c++) acc[c] = fmaf(Xl[rbase + c][hh], w, acc[c]);
    }
    __syncthreads();
  }
  int rbase = (t >> 6) * 8;
#pragma unroll
  for (int c = 0; c < 8; c++) {
    float v = acc[c] + bias;
    T[rbase + c][k] = v;
    float sq = v * v;
#pragma unroll
    for (int off = 32; off; off >>= 1) sq += __shfl_xor(sq, off, 64);
    if (k == 0) norms[r0 + rbase + c] = sq;
  }
  __syncthreads();
#pragma unroll
  for (int p = 0; p < 8; p++) {
    int idx = p * 256 + t;
    int kk = idx >> 5, rr = idx & 31;
    qwT[(size_t)kk * ROWS_TOT + r0 + rr] = T[rr][kk];
  }
}

// ---------------------------------------------------------------------------
// Kernel 2: e[b,n,m] = exp(-dist) -> bf16 in d_out, plus per-batch
// sum/sumsq/max.  128x128 tile, 2x32 k-stages (round-7-proven config).
// ---------------------------------------------------------------------------
__global__ __launch_bounds__(256) void dist_kernel(
    const float* __restrict__ qwT, const float* __restrict__ norms,
    ushort_t* __restrict__ e, float* __restrict__ stats) {
  __shared__ float xtT[32][128];
  __shared__ float ytT[32][128];
  int t = threadIdx.x;
  int b = blockIdx.z;
  int n0 = blockIdx.x * 128, m0 = blockIdx.y * 128;
  int xbase = b * N + n0;
  int ybase = B * N + b * M + m0;

  int w = t >> 6, lane = t & 63;
  int ri = (w >> 1) * 64 + (lane >> 3) * 8;
  int ci = (w & 1) * 64 + (lane & 7) * 8;

  float acc[8][8] = {};
  for (int kc = 0; kc < 64; kc += 32) {
    if (kc) __syncthreads();
#pragma unroll
    for (int p = 0; p < 4; p++) {
      int idx = p * 256 + t;
      int kk = idx >> 5, seg = (idx & 31) * 4;
      *(float4*)&xtT[kk][seg] =
          *(const float4*)(qwT + (size_t)(kc + kk) * ROWS_TOT + xbase + seg);
      *(float4*)&ytT[kk][seg] =
          *(const float4*)(qwT + (size_t)(kc + kk) * ROWS_TOT + ybase + seg);
    }
    __syncthreads();
#pragma unroll 4
    for (int kk = 0; kk < 32; kk++) {
      float4 a0 = *(const float4*)&xtT[kk][ri];
      float4 a1 = *(const float4*)&xtT[kk][ri + 4];
      float4 b0 = *(const float4*)&ytT[kk][ci];
      float4 b1 = *(const float4*)&ytT[kk][ci + 4];
      float av[8] = {a0.x, a0.y, a0.z, a0.w, a1.x, a1.y, a1.z, a1.w};
      float bv[8] = {b0.x, b0.y, b0.z, b0.w, b1.x, b1.y, b1.z, b1.w};
#pragma unroll
      for (int i = 0; i < 8; i++)
#pragma unroll
        for (int j = 0; j < 8; j++) acc[i][j] = fmaf(av[i], bv[j], acc[i][j]);
    }
  }

  float4 xnA = *(const float4*)(norms + b * N + n0 + ri);
  float4 xnB = *(const float4*)(norms + b * N + n0 + ri + 4);
  float4 ynA = *(const float4*)(norms + B * N + b * M + m0 + ci);
  float4 ynB = *(const float4*)(norms + B * N + b * M + m0 + ci + 4);
  float xv[8] = {xnA.x, xnA.y, xnA.z, xnA.w, xnB.x, xnB.y, xnB.z, xnB.w};
  float yv[8] = {ynA.x, ynA.y, ynA.z, ynA.w, ynB.x, ynB.y, ynB.z, ynB.w};

  float lsum = 0.0f, lsq = 0.0f, lmax = 0.0f;
#pragma unroll
  for (int i = 0; i < 8; i++) {
    float o[8];
#pragma unroll
    for (int j = 0; j < 8; j++) {
      float d = xv[i] + yv[j] - 2.0f * acc[i][j];
      float v = __expf(-d);
      o[j] = v;
      lsum += v;
      lsq += v * v;
      lmax = fmaxf(lmax, v);
    }
    uint4 pk;
    pk.x = bf16rn(o[0]) | (bf16rn(o[1]) << 16);
    pk.y = bf16rn(o[2]) | (bf16rn(o[3]) << 16);
    pk.z = bf16rn(o[4]) | (bf16rn(o[5]) << 16);
    pk.w = bf16rn(o[6]) | (bf16rn(o[7]) << 16);
    size_t row = (size_t)(b * N + n0 + ri + i);
    *(uint4*)(e + row * M + m0 + ci) = pk;
  }

#pragma unroll
  for (int off = 32; off; off >>= 1) {
    lsum += __shfl_xor(lsum, off, 64);
    lsq += __shfl_xor(lsq, off, 64);
    lmax = fmaxf(lmax, __shfl_xor(lmax, off, 64));
  }
  __syncthreads();
  float* scr = (float*)xtT;
  if (lane == 0) { scr[w] = lsum; scr[4 + w] = lsq; scr[8 + w] = lmax; }
  __syncthreads();
  if (t == 0) {
    float ssum = scr[0] + scr[1] + scr[2] + scr[3];
    float ssq = scr[4] + scr[5] + scr[6] + scr[7];
    float smax = fmaxf(fmaxf(scr[8], scr[9]), fmaxf(scr[10], scr[11]));
    atomicAdd(&stats[b * 4 + 0], ssum);
    atomicAdd(&stats[b * 4 + 1], ssq);
    atomicMax((unsigned int*)&stats[b * 4 + 2], __float_as_uint(smax));
  }
}

// ---------------------------------------------------------------------------
// Kernel 3: per-batch params.
// params[b*8] = {sL = s*log2e, c0L = (t-2KK)*log2e, KK, enk=e^-KK, ekk=e^KK}
// ---------------------------------------------------------------------------
__global__ void params_kernel(const float* __restrict__ stats,
                              const float* __restrict__ in_w,
                              const float* __restrict__ in_b,
                              float* __restrict__ params) {
  int b = threadIdx.x;
  if (b >= B) return;
  float NMf = (float)N * (float)M;
  float mean = stats[b * 4 + 0] / NMf;
  float var = stats[b * 4 + 1] / NMf - mean * mean;
  var = fmaxf(var, 0.0f);
  float stdv = sqrtf(var + EPS_IN);
  float s = in_w[0] / stdv;
  float t = in_b[0] - mean * s;
  float emax = __uint_as_float(((const unsigned int*)stats)[b * 4 + 2]);
  float Amax = fmaxf(fmaf(s, emax, t), t);
  float KK = fmaxf(Amax - 60.0f, 0.0f);
  params[b * 8 + 0] = s * LOG2E;
  params[b * 8 + 1] = (t - 2.0f * KK) * LOG2E;
  params[b * 8 + 2] = KK;
  params[b * 8 + 3] = __expf(-KK);
  params[b * 8 + 4] = __expf(KK);
}

// Zero all three colsum rotation buffers (24576 floats).
__global__ void csinit_kernel(float* __restrict__ csb) {
  int g = blockIdx.x * 256 + threadIdx.x;
  *(float4*)(csb + g * 4) = float4{0.f, 0.f, 0.f, 0.f};
}

// ---------------------------------------------------------------------------
// Kernel 5: fused sinkhorn iteration (round-7 structure: 8 rows/block,
// 2 rows/wave, 1024 blocks).  NEW: PASS1 keeps p in named float4 registers,
// PASS2 is full-rate fma(p,g,acc) (no second exp2 pass, no C2 re-read).
// All 8 e-loads issued before the prologue so HBM/L3 latency hides under
// the C2 log computation.  Epilogue atomics wave-coalesced (round-7-proven).
// ---------------------------------------------------------------------------
#define PASS1(uu, off, PA, PB)                           \
  {                                                      \
    float4 ca = *(const float4*)&C2a[(off) + ln4];       \
    float4 cb = *(const float4*)&C2b[(off) + ln4];       \
    PA.x = fexp2(fmaf(blo(uu.x), sL, ca.x));             \
    PA.y = fexp2(fmaf(bhi(uu.x), sL, ca.y));             \
    PA.z = fexp2(fmaf(blo(uu.y), sL, ca.z));             \
    PA.w = fexp2(fmaf(bhi(uu.y), sL, ca.w));             \
    PB.x = fexp2(fmaf(blo(uu.z), sL, cb.x));             \
    PB.y = fexp2(fmaf(bhi(uu.z), sL, cb.y));             \
    PB.z = fexp2(fmaf(blo(uu.w), sL, cb.z));             \
    PB.w = fexp2(fmaf(bhi(uu.w), sL, cb.w));             \
    s0 += PA.x + PB.x;                                   \
    s1 += PA.y + PB.y;                                   \
    s2 += PA.z + PB.z;                                   \
    s3 += PA.w + PB.w;                                   \
  }

#define PASS2(PA, PB, AA, BB)                            \
  {                                                      \
    AA.x = fmaf(PA.x, g, AA.x);                          \
    AA.y = fmaf(PA.y, g, AA.y);                          \
    AA.z = fmaf(PA.z, g, AA.z);                          \
    AA.w = fmaf(PA.w, g, AA.w);                          \
    BB.x = fmaf(PB.x, g, BB.x);                          \
    BB.y = fmaf(PB.y, g, BB.y);                          \
    BB.z = fmaf(PB.z, g, BB.z);                          \
    BB.w = fmaf(PB.w, g, BB.w);                          \
  }

__global__ __launch_bounds__(256) void sink_pass(
    const ushort_t* __restrict__ e, const float* __restrict__ params,
    const float* __restrict__ cs_cur, float* __restrict__ cs_nxt,
    float* __restrict__ cs_zz, float* __restrict__ R) {
  __shared__ __align__(16) float C2a[1024], C2b[1024];
  __shared__ __align__(16) float Ds[2048];
  __shared__ __align__(16) float colA[1024], colB[1024];
  int t = threadIdx.x;
  int b = blockIdx.y, blk = blockIdx.x;  // blk 0..255
  int w = t >> 6, lane = t & 63;
  int ln4 = lane * 4;
  const float* pr = params + b * 8;
  float sL = pr[0], c0L = pr[1], KK = pr[2], enk = pr[3], ekk = pr[4];

  // issue both rows' e-loads FIRST: latency hides under the prologue
  int r0 = blk * 8 + w * 2;
  const ushort_t* ep = e + (size_t)(b * N + r0) * M + lane * 8;
  uint4 u0 = *(const uint4*)(ep);
  uint4 u1 = *(const uint4*)(ep + 512);
  uint4 u2 = *(const uint4*)(ep + 1024);
  uint4 u3 = *(const uint4*)(ep + 1536);
  const ushort_t* ep2 = ep + M;
  uint4 v0 = *(const uint4*)(ep2);
  uint4 v1 = *(const uint4*)(ep2 + 512);
  uint4 v2 = *(const uint4*)(ep2 + 1024);
  uint4 v3 = *(const uint4*)(ep2 + 1536);

  if (blk == 0) {  // coalesced zero of next iteration's accumulator
#pragma unroll
    for (int k = 0; k < 2; k++)
      *(float4*)(cs_zz + b * M + (k * 256 + t) * 4) = float4{0.f, 0.f, 0.f, 0.f};
  }
  {  // prologue: thread t owns columns [t*8, t*8+8)
    float4 c0 = *(const float4*)(cs_cur + b * M + t * 8);
    float4 c1 = *(const float4*)(cs_cur + b * M + t * 8 + 4);
    c0.x += enk; c0.y += enk; c0.z += enk; c0.w += enk;
    c1.x += enk; c1.y += enk; c1.z += enk; c1.w += enk;
    float4 ca, cb;
    ca.x = c0L - flog2(c0.x); ca.y = c0L - flog2(c0.y);
    ca.z = c0L - flog2(c0.z); ca.w = c0L - flog2(c0.w);
    cb.x = c0L - flog2(c1.x); cb.y = c0L - flog2(c1.y);
    cb.z = c0L - flog2(c1.z); cb.w = c0L - flog2(c1.w);
    *(float4*)&C2a[w * 256 + ln4] = ca;
    *(float4*)&C2b[w * 256 + ln4] = cb;
    float4 d0 = {ekk * c0.x, ekk * c0.y, ekk * c0.z, ekk * c0.w};
    float4 d1 = {ekk * c1.x, ekk * c1.y, ekk * c1.z, ekk * c1.w};
    *(float4*)&Ds[t * 8] = d0;  // Ds is plain column-indexed
    *(float4*)&Ds[t * 8 + 4] = d1;
  }
  __syncthreads();

  float4 accA0 = {0,0,0,0}, accA1 = {0,0,0,0}, accA2 = {0,0,0,0}, accA3 = {0,0,0,0};
  float4 accB0 = {0,0,0,0}, accB1 = {0,0,0,0}, accB2 = {0,0,0,0}, accB3 = {0,0,0,0};
  float4 pA0, pA1, pA2, pA3, pB0, pB1, pB2, pB3;

  // ---- row 0 ----
  {
    float s0 = 0, s1 = 0, s2 = 0, s3 = 0;
    PASS1(u0, 0, pA0, pB0)
    PASS1(u1, 256, pA1, pB1)
    PASS1(u2, 512, pA2, pB2)
    PASS1(u3, 768, pA3, pB3)
    float sum = (s0 + s1) + (s2 + s3);
#pragma unroll
    for (int off = 32; off; off >>= 1) sum += __shfl_xor(sum, off, 64);
    float sumtot = sum + enk;
    float ls = flog2(sumtot);
    if (lane == 0) R[b * N + r0] = KK + LN2 * ls;
    float g = fexp2(-KK * LOG2E - ls);  // g = enk/sumtot
    PASS2(pA0, pB0, accA0, accB0)
    PASS2(pA1, pB1, accA1, accB1)
    PASS2(pA2, pB2, accA2, accB2)
    PASS2(pA3, pB3, accA3, accB3)
  }
  // ---- row 1 ----
  {
    float s0 = 0, s1 = 0, s2 = 0, s3 = 0;
    PASS1(v0, 0, pA0, pB0)
    PASS1(v1, 256, pA1, pB1)
    PASS1(v2, 512, pA2, pB2)
    PASS1(v3, 768, pA3, pB3)
    float sum = (s0 + s1) + (s2 + s3);
#pragma unroll
    for (int off = 32; off; off >>= 1) sum += __shfl_xor(sum, off, 64);
    float sumtot = sum + enk;
    float ls = flog2(sumtot);
    if (lane == 0) R[b * N + r0 + 1] = KK + LN2 * ls;
    float g = fexp2(-KK * LOG2E - ls);
    PASS2(pA0, pB0, accA0, accB0)
    PASS2(pA1, pB1, accA1, accB1)
    PASS2(pA2, pB2, accA2, accB2)
    PASS2(pA3, pB3, accA3, accB3)
  }

  // combine the 4 waves' column partials in LDS (permuted layout)
  for (int ww = 0; ww < 4; ww++) {
    if (w == ww) {
      if (ww == 0) {
        *(float4*)&colA[ln4] = accA0;
        *(float4*)&colA[256 + ln4] = accA1;
        *(float4*)&colA[512 + ln4] = accA2;
        *(float4*)&colA[768 + ln4] = accA3;
        *(float4*)&colB[ln4] = accB0;
        *(float4*)&colB[256 + ln4] = accB1;
        *(float4*)&colB[512 + ln4] = accB2;
        *(float4*)&colB[768 + ln4] = accB3;
      } else {
        float4 q;
        q = *(float4*)&colA[ln4];
        q.x += accA0.x; q.y += accA0.y; q.z += accA0.z; q.w += accA0.w;
        *(float4*)&colA[ln4] = q;
        q = *(float4*)&colA[256 + ln4];
        q.x += accA1.x; q.y += accA1.y; q.z += accA1.z; q.w += accA1.w;
        *(float4*)&colA[256 + ln4] = q;
        q = *(float4*)&colA[512 + ln4];
        q.x += accA2.x; q.y += accA2.y; q.z += accA2.z; q.w += accA2.w;
        *(float4*)&colA[512 + ln4] = q;
        q = *(float4*)&colA[768 + ln4];
        q.x += accA3.x; q.y += accA3.y; q.z += accA3.z; q.w += accA3.w;
        *(float4*)&colA[768 + ln4] = q;
        q = *(float4*)&colB[ln4];
        q.x += accB0.x; q.y += accB0.y; q.z += accB0.z; q.w += accB0.w;
        *(float4*)&colB[ln4] = q;
        q = *(float4*)&colB[256 + ln4];
        q.x += accB1.x; q.y += accB1.y; q.z += accB1.z; q.w += accB1.w;
        *(float4*)&colB[256 + ln4] = q;
        q = *(float4*)&colB[512 + ln4];
        q.x += accB2.x; q.y += accB2.y; q.z += accB2.z; q.w += accB2.w;
        *(float4*)&colB[512 + ln4] = q;
        q = *(float4*)&colB[768 + ln4];
        q.x += accB3.x; q.y += accB3.y; q.z += accB3.z; q.w += accB3.w;
        *(float4*)&colB[768 + ln4] = q;
      }
    }
    __syncthreads();
  }
  {  // epilogue: WAVE-COALESCED atomics; thread t owns columns {k*256+t}.
    int q = t & 7;
    const float* srcb = (q < 4) ? colA : colB;
    int qq = q & 3;
#pragma unroll
    for (int k = 0; k < 8; k++) {
      int j = k * 256 + t;
      int idx = (j >> 9) * 256 + ((j >> 3) & 63) * 4 + qq;
      atomicAdd(&cs_nxt[b * M + j], srcb[idx] * Ds[j]);
    }
  }
}

// ---------------------------------------------------------------------------
// Kernel 7: aw[i] = exp2(max_j fma(e,sL,C2L_j) + (KK - R_i)*log2e).
// ---------------------------------------------------------------------------
__global__ __launch_bounds__(256) void awmax_kernel(
    const ushort_t* __restrict__ e, const float* __restrict__ params,
    const float* __restrict__ cs_fin, const float* __restrict__ R,
    float* __restrict__ aw) {
  __shared__ __align__(16) float C2a[1024], C2b[1024];
  int t = threadIdx.x;
  int b = blockIdx.y, blk = blockIdx.x;
  const float* pr = params + b * 8;
  float sL = pr[0], c0L = pr[1], KK = pr[2], enk = pr[3];
  {
    float4 v0 = *(const float4*)(cs_fin + b * M + t * 8);
    float4 v1 = *(const float4*)(cs_fin + b * M + t * 8 + 4);
    float4 ca, cb;
    ca.x = c0L - flog2(v0.x + enk); ca.y = c0L - flog2(v0.y + enk);
    ca.z = c0L - flog2(v0.z + enk); ca.w = c0L - flog2(v0.w + enk);
    cb.x = c0L - flog2(v1.x + enk); cb.y = c0L - flog2(v1.y + enk);
    cb.z = c0L - flog2(v1.z + enk); cb.w = c0L - flog2(v1.w + enk);
    int it = t >> 6, ln = t & 63;
    *(float4*)&C2a[it * 256 + ln * 4] = ca;
    *(float4*)&C2b[it * 256 + ln * 4] = cb;
  }
  __syncthreads();

  int w = t >> 6, lane = t & 63;
  int ln4 = lane * 4;
  int r0 = blk * 16 + w * 4;
  const ushort_t* erow = e + (size_t)(b * N + r0) * M;
#pragma unroll
  for (int rr = 0; rr < 4; rr++) {
    float mx = -3.4e38f;
#pragma unroll
    for (int it = 0; it < 4; it++) {
      uint4 u = *(const uint4*)(erow + (size_t)rr * M + it * 512 + lane * 8);
      float4 ca = *(const float4*)&C2a[it * 256 + ln4];
      float4 cb = *(const float4*)&C2b[it * 256 + ln4];
      mx = fmaxf(mx, fmaf(blo(u.x), sL, ca.x));
      mx = fmaxf(mx, fmaf(bhi(u.x), sL, ca.y));
      mx = fmaxf(mx, fmaf(blo(u.y), sL, ca.z));
      mx = fmaxf(mx, fmaf(bhi(u.y), sL, ca.w));
      mx = fmaxf(mx, fmaf(blo(u.z), sL, cb.x));
      mx = fmaxf(mx, fmaf(bhi(u.z), sL, cb.y));
      mx = fmaxf(mx, fmaf(blo(u.w), sL, cb.z));
      mx = fmaxf(mx, fmaf(bhi(u.w), sL, cb.w));
    }
#pragma unroll
    for (int off = 32; off; off >>= 1) mx = fmaxf(mx, __shfl_xor(mx, off, 64));
    if (lane == 0) {
      float Rr = R[b * N + r0 + rr];
      aw[b * N + r0 + rr] = fexp2(mx + (KK - Rr) * LOG2E);
    }
  }
}

// ---------------------------------------------------------------------------
// Kernel 8: out[b,n,m] = aw[b,n] * aw[b,m], float4 stores.
// ---------------------------------------------------------------------------
__global__ __launch_bounds__(256) void outer_kernel(const float* __restrict__ aw,
                                                    float* __restrict__ out) {
  size_t idx = (size_t)blockIdx.x * 256 + threadIdx.x;
  int b = (int)(idx >> 20);
  size_t rem = idx & ((1u << 20) - 1);
  int n = (int)(rem >> 9);
  int m4 = (int)(rem & 511) << 2;
  float a = aw[b * N + n];
  float4 wv = *(const float4*)(aw + b * N + m4);
  float4 o = {a * wv.x, a * wv.y, a * wv.z, a * wv.w};
  *(float4*)(out + (idx << 2)) = o;
}

// ---------------------------------------------------------------------------
extern "C" void kernel_launch(void* const* d_in, const int* in_sizes, int n_in,
                              void* d_out, int out_size, void* d_ws, size_t ws_size,
                              hipStream_t stream) {
  const float* x = (const float*)d_in[0];
  const float* y = (const float*)d_in[1];
  const float* Wq = (const float*)d_in[2];
  const float* bq = (const float*)d_in[3];
  const float* in_w = (const float*)d_in[4];
  const float* in_b = (const float*)d_in[5];
  ushort_t* e = (ushort_t*)d_out;  // 33.5 MB bf16 scratch; overwritten by outer

  float* ws = (float*)d_ws;
  float* qwT = ws;                   // 1048576
  float* norms = ws + 1048576;       // 16384
  float* R = norms + 16384;          // 8192
  float* csb0 = R + 8192;            // 8192
  float* csb1 = csb0 + 8192;         // 8192
  float* csb2 = csb1 + 8192;         // 8192
  float* aw = csb2 + 8192;           // 8192
  float* stats = aw + 8192;          // 32
  float* params = stats + 32;        // 32
  float* csb[3] = {csb0, csb1, csb2};

  proj_kernel<<<512, 256, 0, stream>>>(x, y, Wq, bq, qwT, norms, stats);
  dist_kernel<<<dim3(16, 16, B), 256, 0, stream>>>(qwT, norms, e, stats);
  params_kernel<<<1, 64, 0, stream>>>(stats, in_w, in_b, params);
  csinit_kernel<<<24, 256, 0, stream>>>(csb0);  // zeroes csb0..csb2

  for (int it = 0; it < ITERS; it++) {
    sink_pass<<<dim3(256, B), 256, 0, stream>>>(
        e, params, csb[it % 3], csb[(it + 1) % 3], csb[(it + 2) % 3], R);
  }
  awmax_kernel<<<dim3(128, B), 256, 0, stream>>>(e, params, csb[ITERS % 3], R, aw);
  outer_kernel<<<16384, 256, 0, stream>>>(aw, (float*)d_out);
}

// Round 12
// 418.619 us; speedup vs baseline: 1.8408x; 1.0003x over previous
//
#include <hip/hip_runtime.h>
#include <hip/hip_bf16.h>

// Problem constants
constexpr int B = 4, N = 2048, M = 2048, H = 512, ITERS = 20;
constexpr int ROWS_TOT = B * (N + M);  // 16384
constexpr float EPS_IN = 1e-5f;
constexpr float LOG2E = 1.4426950408889634f;
constexpr float LN2 = 0.6931471805599453f;

typedef unsigned short ushort_t;
typedef unsigned int uint_t;

__device__ __forceinline__ float fexp2(float x) { return __builtin_amdgcn_exp2f(x); }
__device__ __forceinline__ float flog2(float x) { return __builtin_amdgcn_logf(x); }
__device__ __forceinline__ float blo(uint_t v) { return __uint_as_float(v << 16); }
__device__ __forceinline__ float bhi(uint_t v) { return __uint_as_float(v & 0xffff0000u); }
// round-to-nearest-even f32 -> bf16 (inputs finite)
__device__ __forceinline__ uint_t bf16rn(float f) {
  uint_t x = __float_as_uint(f);
  return (x + 0x7fffu + ((x >> 16) & 1u)) >> 16;
}

// ---------------------------------------------------------------------------
// Kernel 1: projections -> qwT[k][row] (64 x 16384), plus per-row sq norms.
// ---------------------------------------------------------------------------
__global__ __launch_bounds__(256) void proj_kernel(
    const float* __restrict__ x, const float* __restrict__ y,
    const float* __restrict__ Wq, const float* __restrict__ bq,
    float* __restrict__ qwT, float* __restrict__ norms, float* __restrict__ stats) {
  __shared__ float Wl[64][65];
  __shared__ float Xl[32][65];
  __shared__ float T[32][65];
  int t = threadIdx.x;
  int r0 = blockIdx.x * 32;
  const float* src = (r0 < B * N) ? x + (size_t)r0 * H
                                  : y + (size_t)(r0 - B * N) * H;
  if (blockIdx.x == 0 && t < 32) stats[t] = 0.0f;

  int k = t & 63;
  float bias = bq[k];
  float acc[8];
#pragma unroll
  for (int c = 0; c < 8; c++) acc[c] = 0.0f;

  for (int hc = 0; hc < H; hc += 64) {
#pragma unroll
    for (int l = 0; l < 16; l++) {
      int idx = t + l * 256;
      int kk = idx >> 6, hh = idx & 63;
      Wl[kk][hh] = Wq[(size_t)kk * H + hc + hh];
    }
#pragma unroll
    for (int l = 0; l < 8; l++) {
      int idx = t + l * 256;
      int rr = idx >> 6, hh = idx & 63;
      Xl[rr][hh] = src[(size_t)rr * H + hc + hh];
    }
    __syncthreads();
    int rbase = (t >> 6) * 8;
#pragma unroll
    for (int hh = 0; hh < 64; hh++) {
      float w = Wl[k][hh];
#pragma unroll
      for (int c = 0; c < 8; c++) acc[c] = fmaf(Xl[rbase + c][hh], w, acc[c]);
    }
    __syncthreads();
  }
  int rbase = (t >> 6) * 8;
#pragma unroll
  for (int c = 0; c < 8; c++) {
    float v = acc[c] + bias;
    T[rbase + c][k] = v;
    float sq = v * v;
#pragma unroll
    for (int off = 32; off; off >>= 1) sq += __shfl_xor(sq, off, 64);
    if (k == 0) norms[r0 + rbase + c] = sq;
  }
  __syncthreads();
#pragma unroll
  for (int p = 0; p < 8; p++) {
    int idx = p * 256 + t;
    int kk = idx >> 5, rr = idx & 31;
    qwT[(size_t)kk * ROWS_TOT + r0 + rr] = T[rr][kk];
  }
}

// ---------------------------------------------------------------------------
// Kernel 2: e[b,n,m] = exp(-dist) -> bf16 in d_out, plus per-batch
// sum/sumsq/max.  128x128 tile, 2x32 k-stages (round-7/9-proven config).
// ---------------------------------------------------------------------------
__global__ __launch_bounds__(256) void dist_kernel(
    const float* __restrict__ qwT, const float* __restrict__ norms,
    ushort_t* __restrict__ e, float* __restrict__ stats) {
  __shared__ float xtT[32][128];
  __shared__ float ytT[32][128];
  int t = threadIdx.x;
  int b = blockIdx.z;
  int n0 = blockIdx.x * 128, m0 = blockIdx.y * 128;
  int xbase = b * N + n0;
  int ybase = B * N + b * M + m0;

  int w = t >> 6, lane = t & 63;
  int ri = (w >> 1) * 64 + (lane >> 3) * 8;
  int ci = (w & 1) * 64 + (lane & 7) * 8;

  float acc[8][8] = {};
  for (int kc = 0; kc < 64; kc += 32) {
    if (kc) __syncthreads();
#pragma unroll
    for (int p = 0; p < 4; p++) {
      int idx = p * 256 + t;
      int kk = idx >> 5, seg = (idx & 31) * 4;
      *(float4*)&xtT[kk][seg] =
          *(const float4*)(qwT + (size_t)(kc + kk) * ROWS_TOT + xbase + seg);
      *(float4*)&ytT[kk][seg] =
          *(const float4*)(qwT + (size_t)(kc + kk) * ROWS_TOT + ybase + seg);
    }
    __syncthreads();
#pragma unroll 4
    for (int kk = 0; kk < 32; kk++) {
      float4 a0 = *(const float4*)&xtT[kk][ri];
      float4 a1 = *(const float4*)&xtT[kk][ri + 4];
      float4 b0 = *(const float4*)&ytT[kk][ci];
      float4 b1 = *(const float4*)&ytT[kk][ci + 4];
      float av[8] = {a0.x, a0.y, a0.z, a0.w, a1.x, a1.y, a1.z, a1.w};
      float bv[8] = {b0.x, b0.y, b0.z, b0.w, b1.x, b1.y, b1.z, b1.w};
#pragma unroll
      for (int i = 0; i < 8; i++)
#pragma unroll
        for (int j = 0; j < 8; j++) acc[i][j] = fmaf(av[i], bv[j], acc[i][j]);
    }
  }

  float4 xnA = *(const float4*)(norms + b * N + n0 + ri);
  float4 xnB = *(const float4*)(norms + b * N + n0 + ri + 4);
  float4 ynA = *(const float4*)(norms + B * N + b * M + m0 + ci);
  float4 ynB = *(const float4*)(norms + B * N + b * M + m0 + ci + 4);
  float xv[8] = {xnA.x, xnA.y, xnA.z, xnA.w, xnB.x, xnB.y, xnB.z, xnB.w};
  float yv[8] = {ynA.x, ynA.y, ynA.z, ynA.w, ynB.x, ynB.y, ynB.z, ynB.w};

  float lsum = 0.0f, lsq = 0.0f, lmax = 0.0f;
#pragma unroll
  for (int i = 0; i < 8; i++) {
    float o[8];
#pragma unroll
    for (int j = 0; j < 8; j++) {
      float d = xv[i] + yv[j] - 2.0f * acc[i][j];
      float v = __expf(-d);
      o[j] = v;
      lsum += v;
      lsq += v * v;
      lmax = fmaxf(lmax, v);
    }
    uint4 pk;
    pk.x = bf16rn(o[0]) | (bf16rn(o[1]) << 16);
    pk.y = bf16rn(o[2]) | (bf16rn(o[3]) << 16);
    pk.z = bf16rn(o[4]) | (bf16rn(o[5]) << 16);
    pk.w = bf16rn(o[6]) | (bf16rn(o[7]) << 16);
    size_t row = (size_t)(b * N + n0 + ri + i);
    *(uint4*)(e + row * M + m0 + ci) = pk;
  }

#pragma unroll
  for (int off = 32; off; off >>= 1) {
    lsum += __shfl_xor(lsum, off, 64);
    lsq += __shfl_xor(lsq, off, 64);
    lmax = fmaxf(lmax, __shfl_xor(lmax, off, 64));
  }
  __syncthreads();
  float* scr = (float*)xtT;
  if (lane == 0) { scr[w] = lsum; scr[4 + w] = lsq; scr[8 + w] = lmax; }
  __syncthreads();
  if (t == 0) {
    float ssum = scr[0] + scr[1] + scr[2] + scr[3];
    float ssq = scr[4] + scr[5] + scr[6] + scr[7];
    float smax = fmaxf(fmaxf(scr[8], scr[9]), fmaxf(scr[10], scr[11]));
    atomicAdd(&stats[b * 4 + 0], ssum);
    atomicAdd(&stats[b * 4 + 1], ssq);
    atomicMax((unsigned int*)&stats[b * 4 + 2], __float_as_uint(smax));
  }
}

// ---------------------------------------------------------------------------
// Kernel 3: per-batch params + zero the three colsum rotation buffers.
// params[b*8] = {sL = s*log2e, c0L = (t-2KK)*log2e, KK, enk=e^-KK, ekk=e^KK}
// Grid 24 x 256: all threads zero csb (24576 floats); block 0 threads 0..3
// compute the per-batch params.
// ---------------------------------------------------------------------------
__global__ void params_csinit_kernel(const float* __restrict__ stats,
                                     const float* __restrict__ in_w,
                                     const float* __restrict__ in_b,
                                     float* __restrict__ params,
                                     float* __restrict__ csb) {
  int g = blockIdx.x * 256 + threadIdx.x;  // 0..6143 float4s
  *(float4*)(csb + g * 4) = float4{0.f, 0.f, 0.f, 0.f};
  if (blockIdx.x == 0 && threadIdx.x < B) {
    int b = threadIdx.x;
    float NMf = (float)N * (float)M;
    float mean = stats[b * 4 + 0] / NMf;
    float var = stats[b * 4 + 1] / NMf - mean * mean;
    var = fmaxf(var, 0.0f);
    float stdv = sqrtf(var + EPS_IN);
    float s = in_w[0] / stdv;
    float t = in_b[0] - mean * s;
    float emax = __uint_as_float(((const unsigned int*)stats)[b * 4 + 2]);
    float Amax = fmaxf(fmaf(s, emax, t), t);
    float KK = fmaxf(Amax - 60.0f, 0.0f);
    params[b * 8 + 0] = s * LOG2E;
    params[b * 8 + 1] = (t - 2.0f * KK) * LOG2E;
    params[b * 8 + 2] = KK;
    params[b * 8 + 3] = __expf(-KK);
    params[b * 8 + 4] = __expf(KK);
  }
}

// ---------------------------------------------------------------------------
// Kernel 5: fused sinkhorn iteration (round-9-proven: 8 rows/block, 2 rows
// per wave, 1024 blocks).  PASS1 keeps p in named float4 registers, PASS2 is
// full-rate fma(p,g,acc).  All 8 e-loads issued before the prologue so
// HBM/L3 latency hides under the C2 log computation.  Epilogue atomics
// wave-coalesced (round-7-proven).
// ---------------------------------------------------------------------------
#define PASS1(uu, off, PA, PB)                           \
  {                                                      \
    float4 ca = *(const float4*)&C2a[(off) + ln4];       \
    float4 cb = *(const float4*)&C2b[(off) + ln4];       \
    PA.x = fexp2(fmaf(blo(uu.x), sL, ca.x));             \
    PA.y = fexp2(fmaf(bhi(uu.x), sL, ca.y));             \
    PA.z = fexp2(fmaf(blo(uu.y), sL, ca.z));             \
    PA.w = fexp2(fmaf(bhi(uu.y), sL, ca.w));             \
    PB.x = fexp2(fmaf(blo(uu.z), sL, cb.x));             \
    PB.y = fexp2(fmaf(bhi(uu.z), sL, cb.y));             \
    PB.z = fexp2(fmaf(blo(uu.w), sL, cb.z));             \
    PB.w = fexp2(fmaf(bhi(uu.w), sL, cb.w));             \
    s0 += PA.x + PB.x;                                   \
    s1 += PA.y + PB.y;                                   \
    s2 += PA.z + PB.z;                                   \
    s3 += PA.w + PB.w;                                   \
  }

#define PASS2(PA, PB, AA, BB)                            \
  {                                                      \
    AA.x = fmaf(PA.x, g, AA.x);                          \
    AA.y = fmaf(PA.y, g, AA.y);                          \
    AA.z = fmaf(PA.z, g, AA.z);                          \
    AA.w = fmaf(PA.w, g, AA.w);                          \
    BB.x = fmaf(PB.x, g, BB.x);                          \
    BB.y = fmaf(PB.y, g, BB.y);                          \
    BB.z = fmaf(PB.z, g, BB.z);                          \
    BB.w = fmaf(PB.w, g, BB.w);                          \
  }

__global__ __launch_bounds__(256) void sink_pass(
    const ushort_t* __restrict__ e, const float* __restrict__ params,
    const float* __restrict__ cs_cur, float* __restrict__ cs_nxt,
    float* __restrict__ cs_zz, float* __restrict__ R) {
  __shared__ __align__(16) float C2a[1024], C2b[1024];
  __shared__ __align__(16) float Ds[2048];
  __shared__ __align__(16) float colA[1024], colB[1024];
  int t = threadIdx.x;
  int b = blockIdx.y, blk = blockIdx.x;  // blk 0..255
  int w = t >> 6, lane = t & 63;
  int ln4 = lane * 4;
  const float* pr = params + b * 8;
  float sL = pr[0], c0L = pr[1], KK = pr[2], enk = pr[3], ekk = pr[4];

  // issue both rows' e-loads FIRST: latency hides under the prologue
  int r0 = blk * 8 + w * 2;
  const ushort_t* ep = e + (size_t)(b * N + r0) * M + lane * 8;
  uint4 u0 = *(const uint4*)(ep);
  uint4 u1 = *(const uint4*)(ep + 512);
  uint4 u2 = *(const uint4*)(ep + 1024);
  uint4 u3 = *(const uint4*)(ep + 1536);
  const ushort_t* ep2 = ep + M;
  uint4 v0 = *(const uint4*)(ep2);
  uint4 v1 = *(const uint4*)(ep2 + 512);
  uint4 v2 = *(const uint4*)(ep2 + 1024);
  uint4 v3 = *(const uint4*)(ep2 + 1536);

  if (blk == 0) {  // coalesced zero of next iteration's accumulator
#pragma unroll
    for (int k = 0; k < 2; k++)
      *(float4*)(cs_zz + b * M + (k * 256 + t) * 4) = float4{0.f, 0.f, 0.f, 0.f};
  }
  {  // prologue: thread t owns columns [t*8, t*8+8)
    float4 c0 = *(const float4*)(cs_cur + b * M + t * 8);
    float4 c1 = *(const float4*)(cs_cur + b * M + t * 8 + 4);
    c0.x += enk; c0.y += enk; c0.z += enk; c0.w += enk;
    c1.x += enk; c1.y += enk; c1.z += enk; c1.w += enk;
    float4 ca, cb;
    ca.x = c0L - flog2(c0.x); ca.y = c0L - flog2(c0.y);
    ca.z = c0L - flog2(c0.z); ca.w = c0L - flog2(c0.w);
    cb.x = c0L - flog2(c1.x); cb.y = c0L - flog2(c1.y);
    cb.z = c0L - flog2(c1.z); cb.w = c0L - flog2(c1.w);
    *(float4*)&C2a[w * 256 + ln4] = ca;
    *(float4*)&C2b[w * 256 + ln4] = cb;
    float4 d0 = {ekk * c0.x, ekk * c0.y, ekk * c0.z, ekk * c0.w};
    float4 d1 = {ekk * c1.x, ekk * c1.y, ekk * c1.z, ekk * c1.w};
    *(float4*)&Ds[t * 8] = d0;  // Ds is plain column-indexed
    *(float4*)&Ds[t * 8 + 4] = d1;
  }
  __syncthreads();

  float4 accA0 = {0,0,0,0}, accA1 = {0,0,0,0}, accA2 = {0,0,0,0}, accA3 = {0,0,0,0};
  float4 accB0 = {0,0,0,0}, accB1 = {0,0,0,0}, accB2 = {0,0,0,0}, accB3 = {0,0,0,0};
  float4 pA0, pA1, pA2, pA3, pB0, pB1, pB2, pB3;

  // ---- row 0 ----
  {
    float s0 = 0, s1 = 0, s2 = 0, s3 = 0;
    PASS1(u0, 0, pA0, pB0)
    PASS1(u1, 256, pA1, pB1)
    PASS1(u2, 512, pA2, pB2)
    PASS1(u3, 768, pA3, pB3)
    float sum = (s0 + s1) + (s2 + s3);
#pragma unroll
    for (int off = 32; off; off >>= 1) sum += __shfl_xor(sum, off, 64);
    float sumtot = sum + enk;
    float ls = flog2(sumtot);
    if (lane == 0) R[b * N + r0] = KK + LN2 * ls;
    float g = fexp2(-KK * LOG2E - ls);  // g = enk/sumtot
    PASS2(pA0, pB0, accA0, accB0)
    PASS2(pA1, pB1, accA1, accB1)
    PASS2(pA2, pB2, accA2, accB2)
    PASS2(pA3, pB3, accA3, accB3)
  }
  // ---- row 1 ----
  {
    float s0 = 0, s1 = 0, s2 = 0, s3 = 0;
    PASS1(v0, 0, pA0, pB0)
    PASS1(v1, 256, pA1, pB1)
    PASS1(v2, 512, pA2, pB2)
    PASS1(v3, 768, pA3, pB3)
    float sum = (s0 + s1) + (s2 + s3);
#pragma unroll
    for (int off = 32; off; off >>= 1) sum += __shfl_xor(sum, off, 64);
    float sumtot = sum + enk;
    float ls = flog2(sumtot);
    if (lane == 0) R[b * N + r0 + 1] = KK + LN2 * ls;
    float g = fexp2(-KK * LOG2E - ls);
    PASS2(pA0, pB0, accA0, accB0)
    PASS2(pA1, pB1, accA1, accB1)
    PASS2(pA2, pB2, accA2, accB2)
    PASS2(pA3, pB3, accA3, accB3)
  }

  // combine the 4 waves' column partials in LDS (permuted layout)
  for (int ww = 0; ww < 4; ww++) {
    if (w == ww) {
      if (ww == 0) {
        *(float4*)&colA[ln4] = accA0;
        *(float4*)&colA[256 + ln4] = accA1;
        *(float4*)&colA[512 + ln4] = accA2;
        *(float4*)&colA[768 + ln4] = accA3;
        *(float4*)&colB[ln4] = accB0;
        *(float4*)&colB[256 + ln4] = accB1;
        *(float4*)&colB[512 + ln4] = accB2;
        *(float4*)&colB[768 + ln4] = accB3;
      } else {
        float4 q;
        q = *(float4*)&colA[ln4];
        q.x += accA0.x; q.y += accA0.y; q.z += accA0.z; q.w += accA0.w;
        *(float4*)&colA[ln4] = q;
        q = *(float4*)&colA[256 + ln4];
        q.x += accA1.x; q.y += accA1.y; q.z += accA1.z; q.w += accA1.w;
        *(float4*)&colA[256 + ln4] = q;
        q = *(float4*)&colA[512 + ln4];
        q.x += accA2.x; q.y += accA2.y; q.z += accA2.z; q.w += accA2.w;
        *(float4*)&colA[512 + ln4] = q;
        q = *(float4*)&colA[768 + ln4];
        q.x += accA3.x; q.y += accA3.y; q.z += accA3.z; q.w += accA3.w;
        *(float4*)&colA[768 + ln4] = q;
        q = *(float4*)&colB[ln4];
        q.x += accB0.x; q.y += accB0.y; q.z += accB0.z; q.w += accB0.w;
        *(float4*)&colB[ln4] = q;
        q = *(float4*)&colB[256 + ln4];
        q.x += accB1.x; q.y += accB1.y; q.z += accB1.z; q.w += accB1.w;
        *(float4*)&colB[256 + ln4] = q;
        q = *(float4*)&colB[512 + ln4];
        q.x += accB2.x; q.y += accB2.y; q.z += accB2.z; q.w += accB2.w;
        *(float4*)&colB[512 + ln4] = q;
        q = *(float4*)&colB[768 + ln4];
        q.x += accB3.x; q.y += accB3.y; q.z += accB3.z; q.w += accB3.w;
        *(float4*)&colB[768 + ln4] = q;
      }
    }
    __syncthreads();
  }
  {  // epilogue: WAVE-COALESCED atomics; thread t owns columns {k*256+t}.
    int q = t & 7;
    const float* srcb = (q < 4) ? colA : colB;
    int qq = q & 3;
#pragma unroll
    for (int k = 0; k < 8; k++) {
      int j = k * 256 + t;
      int idx = (j >> 9) * 256 + ((j >> 3) & 63) * 4 + qq;
      atomicAdd(&cs_nxt[b * M + j], srcb[idx] * Ds[j]);
    }
  }
}

// ---------------------------------------------------------------------------
// Kernel 7: aw[i] = exp2(max_j fma(e,sL,C2L_j) + (KK - R_i)*log2e).
// ---------------------------------------------------------------------------
__global__ __launch_bounds__(256) void awmax_kernel(
    const ushort_t* __restrict__ e, const float* __restrict__ params,
    const float* __restrict__ cs_fin, const float* __restrict__ R,
    float* __restrict__ aw) {
  __shared__ __align__(16) float C2a[1024], C2b[1024];
  int t = threadIdx.x;
  int b = blockIdx.y, blk = blockIdx.x;
  const float* pr = params + b * 8;
  float sL = pr[0], c0L = pr[1], KK = pr[2], enk = pr[3];
  {
    float4 v0 = *(const float4*)(cs_fin + b * M + t * 8);
    float4 v1 = *(const float4*)(cs_fin + b * M + t * 8 + 4);
    float4 ca, cb;
    ca.x = c0L - flog2(v0.x + enk); ca.y = c0L - flog2(v0.y + enk);
    ca.z = c0L - flog2(v0.z + enk); ca.w = c0L - flog2(v0.w + enk);
    cb.x = c0L - flog2(v1.x + enk); cb.y = c0L - flog2(v1.y + enk);
    cb.z = c0L - flog2(v1.z + enk); cb.w = c0L - flog2(v1.w + enk);
    int it = t >> 6, ln = t & 63;
    *(float4*)&C2a[it * 256 + ln * 4] = ca;
    *(float4*)&C2b[it * 256 + ln * 4] = cb;
  }
  __syncthreads();

  int w = t >> 6, lane = t & 63;
  int ln4 = lane * 4;
  int r0 = blk * 16 + w * 4;
  const ushort_t* erow = e + (size_t)(b * N + r0) * M;
#pragma unroll
  for (int rr = 0; rr < 4; rr++) {
    float mx = -3.4e38f;
#pragma unroll
    for (int it = 0; it < 4; it++) {
      uint4 u = *(const uint4*)(erow + (size_t)rr * M + it * 512 + lane * 8);
      float4 ca = *(const float4*)&C2a[it * 256 + ln4];
      float4 cb = *(const float4*)&C2b[it * 256 + ln4];
      mx = fmaxf(mx, fmaf(blo(u.x), sL, ca.x));
      mx = fmaxf(mx, fmaf(bhi(u.x), sL, ca.y));
      mx = fmaxf(mx, fmaf(blo(u.y), sL, ca.z));
      mx = fmaxf(mx, fmaf(bhi(u.y), sL, ca.w));
      mx = fmaxf(mx, fmaf(blo(u.z), sL, cb.x));
      mx = fmaxf(mx, fmaf(bhi(u.z), sL, cb.y));
      mx = fmaxf(mx, fmaf(blo(u.w), sL, cb.z));
      mx = fmaxf(mx, fmaf(bhi(u.w), sL, cb.w));
    }
#pragma unroll
    for (int off = 32; off; off >>= 1) mx = fmaxf(mx, __shfl_xor(mx, off, 64));
    if (lane == 0) {
      float Rr = R[b * N + r0 + rr];
      aw[b * N + r0 + rr] = fexp2(mx + (KK - Rr) * LOG2E);
    }
  }
}

// ---------------------------------------------------------------------------
// Kernel 8: out[b,n,m] = aw[b,n] * aw[b,m], float4 stores.
// ---------------------------------------------------------------------------
__global__ __launch_bounds__(256) void outer_kernel(const float* __restrict__ aw,
                                                    float* __restrict__ out) {
  size_t idx = (size_t)blockIdx.x * 256 + threadIdx.x;
  int b = (int)(idx >> 20);
  size_t rem = idx & ((1u << 20) - 1);
  int n = (int)(rem >> 9);
  int m4 = (int)(rem & 511) << 2;
  float a = aw[b * N + n];
  float4 wv = *(const float4*)(aw + b * N + m4);
  float4 o = {a * wv.x, a * wv.y, a * wv.z, a * wv.w};
  *(float4*)(out + (idx << 2)) = o;
}

// ---------------------------------------------------------------------------
extern "C" void kernel_launch(void* const* d_in, const int* in_sizes, int n_in,
                              void* d_out, int out_size, void* d_ws, size_t ws_size,
                              hipStream_t stream) {
  const float* x = (const float*)d_in[0];
  const float* y = (const float*)d_in[1];
  const float* Wq = (const float*)d_in[2];
  const float* bq = (const float*)d_in[3];
  const float* in_w = (const float*)d_in[4];
  const float* in_b = (const float*)d_in[5];
  ushort_t* e = (ushort_t*)d_out;  // 33.5 MB bf16 scratch; overwritten by outer

  float* ws = (float*)d_ws;
  float* qwT = ws;                   // 1048576
  float* norms = ws + 1048576;       // 16384
  float* R = norms + 16384;          // 8192
  float* csb0 = R + 8192;            // 8192
  float* csb1 = csb0 + 8192;         // 8192
  float* csb2 = csb1 + 8192;         // 8192
  float* aw = csb2 + 8192;           // 8192
  float* stats = aw + 8192;          // 32
  float* params = stats + 32;        // 32
  float* csb[3] = {csb0, csb1, csb2};

  proj_kernel<<<512, 256, 0, stream>>>(x, y, Wq, bq, qwT, norms, stats);
  dist_kernel<<<dim3(16, 16, B), 256, 0, stream>>>(qwT, norms, e, stats);
  params_csinit_kernel<<<24, 256, 0, stream>>>(stats, in_w, in_b, params, csb0);

  for (int it = 0; it < ITERS; it++) {
    sink_pass<<<dim3(256, B), 256, 0, stream>>>(
        e, params, csb[it % 3], csb[(it + 1) % 3], csb[(it + 2) % 3], R);
  }
  awmax_kernel<<<dim3(128, B), 256, 0, stream>>>(e, params, csb[ITERS % 3], R, aw);
  outer_kernel<<<16384, 256, 0, stream>>>(aw, (float*)d_out);
}

// Round 13
// 408.040 us; speedup vs baseline: 1.8885x; 1.0259x over previous
//
#include <hip/hip_runtime.h>
#include <hip/hip_bf16.h>

// Problem constants
constexpr int B = 4, N = 2048, M = 2048, H = 512, ITERS = 20;
constexpr int ROWS_TOT = B * (N + M);  // 16384
constexpr float EPS_IN = 1e-5f;
constexpr float LOG2E = 1.4426950408889634f;
constexpr float LN2 = 0.6931471805599453f;

typedef unsigned short ushort_t;
typedef unsigned int uint_t;
typedef __attribute__((ext_vector_type(8))) short bf16x8;
typedef __attribute__((ext_vector_type(4))) float f32x4;

__device__ __forceinline__ float fexp2(float x) { return __builtin_amdgcn_exp2f(x); }
__device__ __forceinline__ float flog2(float x) { return __builtin_amdgcn_logf(x); }
__device__ __forceinline__ float blo(uint_t v) { return __uint_as_float(v << 16); }
__device__ __forceinline__ float bhi(uint_t v) { return __uint_as_float(v & 0xffff0000u); }
// round-to-nearest-even f32 -> bf16 (inputs finite)
__device__ __forceinline__ uint_t bf16rn(float f) {
  uint_t x = __float_as_uint(f);
  return (x + 0x7fffu + ((x >> 16) & 1u)) >> 16;
}

// ---------------------------------------------------------------------------
// Kernel 1: projections -> qwh[row][k] (16384 x 64, ROW-major bf16 for MFMA
// fragment loads), plus per-row sq norms (f32, from unrounded values).
// ---------------------------------------------------------------------------
__global__ __launch_bounds__(256) void proj_kernel(
    const float* __restrict__ x, const float* __restrict__ y,
    const float* __restrict__ Wq, const float* __restrict__ bq,
    ushort_t* __restrict__ qwh, float* __restrict__ norms, float* __restrict__ stats) {
  __shared__ float Wl[64][65];
  __shared__ float Xl[32][65];
  int t = threadIdx.x;
  int r0 = blockIdx.x * 32;
  const float* src = (r0 < B * N) ? x + (size_t)r0 * H
                                  : y + (size_t)(r0 - B * N) * H;
  if (blockIdx.x == 0 && t < 32) stats[t] = 0.0f;

  int k = t & 63;
  float bias = bq[k];
  float acc[8];
#pragma unroll
  for (int c = 0; c < 8; c++) acc[c] = 0.0f;

  for (int hc = 0; hc < H; hc += 64) {
#pragma unroll
    for (int l = 0; l < 16; l++) {
      int idx = t + l * 256;
      int kk = idx >> 6, hh = idx & 63;
      Wl[kk][hh] = Wq[(size_t)kk * H + hc + hh];
    }
#pragma unroll
    for (int l = 0; l < 8; l++) {
      int idx = t + l * 256;
      int rr = idx >> 6, hh = idx & 63;
      Xl[rr][hh] = src[(size_t)rr * H + hc + hh];
    }
    __syncthreads();
    int rbase = (t >> 6) * 8;
#pragma unroll
    for (int hh = 0; hh < 64; hh++) {
      float w = Wl[k][hh];
#pragma unroll
      for (int c = 0; c < 8; c++) acc[c] = fmaf(Xl[rbase + c][hh], w, acc[c]);
    }
    __syncthreads();
  }
  int rbase = (t >> 6) * 8;
#pragma unroll
  for (int c = 0; c < 8; c++) {
    float v = acc[c] + bias;
    qwh[(size_t)(r0 + rbase + c) * 64 + k] = (ushort_t)bf16rn(v);
    float sq = v * v;
#pragma unroll
    for (int off = 32; off; off >>= 1) sq += __shfl_xor(sq, off, 64);
    if (k == 0) norms[r0 + rbase + c] = sq;
  }
}

// ---------------------------------------------------------------------------
// Kernel 2 (MFMA): e[b,n,m] = exp(-(|xw_n|^2+|yw_m|^2-2 xw.yw)) -> bf16 in
// d_out, plus per-batch sum/sumsq/max.  128x128 tile/block, 4 waves each
// owning a 64x64 sub-tile: 32x mfma_f32_16x16x32_bf16 per wave, fragments
// loaded straight from global qwh (L2-hot).  e-tile staged in padded LDS
// ([128][136] shorts) for coalesced 16-B global stores.
// Correctness note: A and B frags use the identical (lane,elem) addressing,
// so any common intra-frag k-permutation cancels (dot is k-invariant);
// the C/D layout col=lane&15,row=(lane>>4)*4+reg is HW-verified (m89/m91).
// ---------------------------------------------------------------------------
__global__ __launch_bounds__(256) void dist_kernel(
    const ushort_t* __restrict__ qwh, const float* __restrict__ norms,
    ushort_t* __restrict__ e, float* __restrict__ stats) {
  __shared__ __align__(16) ushort_t eT[128 * 136];  // 34 KB
  __shared__ float xnL[128], ynL[128], scr[12];
  int t = threadIdx.x;
  int b = blockIdx.z;
  int n0 = blockIdx.x * 128, m0 = blockIdx.y * 128;
  int w = t >> 6, lane = t & 63;

  if (t < 128) xnL[t] = norms[b * N + n0 + t];
  else ynL[t - 128] = norms[B * N + b * M + m0 + (t - 128)];

  int wr = (w >> 1) * 64, wc = (w & 1) * 64;  // wave sub-tile origin
  int fr = lane & 15, fk = (lane >> 4) * 8;   // frag row/col + k-offset

  f32x4 acc[4][4];
#pragma unroll
  for (int i = 0; i < 4; i++)
#pragma unroll
    for (int j = 0; j < 4; j++) acc[i][j] = (f32x4){0.f, 0.f, 0.f, 0.f};

  const ushort_t* xb = qwh + (size_t)(b * N + n0 + wr + fr) * 64 + fk;
  const ushort_t* yb = qwh + (size_t)(B * N + b * M + m0 + wc + fr) * 64 + fk;
#pragma unroll
  for (int kg = 0; kg < 2; kg++) {
    bf16x8 aF[4], bF[4];
#pragma unroll
    for (int i = 0; i < 4; i++) {
      aF[i] = *(const bf16x8*)(xb + (size_t)i * 16 * 64 + kg * 32);
      bF[i] = *(const bf16x8*)(yb + (size_t)i * 16 * 64 + kg * 32);
    }
#pragma unroll
    for (int i = 0; i < 4; i++)
#pragma unroll
      for (int j = 0; j < 4; j++)
        acc[i][j] = __builtin_amdgcn_mfma_f32_16x16x32_bf16(
            aF[i], bF[j], acc[i][j], 0, 0, 0);
  }
  __syncthreads();  // xnL/ynL ready

  float lsum = 0.0f, lsq = 0.0f, lmax = 0.0f;
#pragma unroll
  for (int i = 0; i < 4; i++) {
    int rl = wr + i * 16 + ((lane >> 4) << 2);
    float xn0 = xnL[rl], xn1 = xnL[rl + 1], xn2 = xnL[rl + 2], xn3 = xnL[rl + 3];
#pragma unroll
    for (int j = 0; j < 4; j++) {
      int cl = wc + j * 16 + (lane & 15);
      float yn_ = ynL[cl];
      float v0 = __expf(-(xn0 + yn_ - 2.0f * acc[i][j][0]));
      float v1 = __expf(-(xn1 + yn_ - 2.0f * acc[i][j][1]));
      float v2 = __expf(-(xn2 + yn_ - 2.0f * acc[i][j][2]));
      float v3 = __expf(-(xn3 + yn_ - 2.0f * acc[i][j][3]));
      lsum += (v0 + v1) + (v2 + v3);
      lsq += (v0 * v0 + v1 * v1) + (v2 * v2 + v3 * v3);
      lmax = fmaxf(fmaxf(lmax, fmaxf(v0, v1)), fmaxf(v2, v3));
      eT[(rl + 0) * 136 + cl] = (ushort_t)bf16rn(v0);
      eT[(rl + 1) * 136 + cl] = (ushort_t)bf16rn(v1);
      eT[(rl + 2) * 136 + cl] = (ushort_t)bf16rn(v2);
      eT[(rl + 3) * 136 + cl] = (ushort_t)bf16rn(v3);
    }
  }
#pragma unroll
  for (int off = 32; off; off >>= 1) {
    lsum += __shfl_xor(lsum, off, 64);
    lsq += __shfl_xor(lsq, off, 64);
    lmax = fmaxf(lmax, __shfl_xor(lmax, off, 64));
  }
  if (lane == 0) { scr[w] = lsum; scr[4 + w] = lsq; scr[8 + w] = lmax; }
  __syncthreads();

  // coalesced write-out: 16 lanes cover one row's 128 shorts (16 B each)
#pragma unroll
  for (int p = 0; p < 8; p++) {
    int row = p * 16 + (t >> 4);
    int cs = (t & 15) * 8;
    uint4 vv = *(const uint4*)&eT[row * 136 + cs];
    *(uint4*)(e + (size_t)(b * N + n0 + row) * M + m0 + cs) = vv;
  }
  if (t == 0) {
    float ssum = scr[0] + scr[1] + scr[2] + scr[3];
    float ssq = scr[4] + scr[5] + scr[6] + scr[7];
    float smax = fmaxf(fmaxf(scr[8], scr[9]), fmaxf(scr[10], scr[11]));
    atomicAdd(&stats[b * 4 + 0], ssum);
    atomicAdd(&stats[b * 4 + 1], ssq);
    atomicMax((unsigned int*)&stats[b * 4 + 2], __float_as_uint(smax));
  }
}

// ---------------------------------------------------------------------------
// Kernel 3: per-batch params + zero the three colsum rotation buffers.
// params[b*8] = {sL = s*log2e, c0L = (t-2KK)*log2e, KK, enk=e^-KK, ekk=e^KK}
// ---------------------------------------------------------------------------
__global__ void params_csinit_kernel(const float* __restrict__ stats,
                                     const float* __restrict__ in_w,
                                     const float* __restrict__ in_b,
                                     float* __restrict__ params,
                                     float* __restrict__ csb) {
  int g = blockIdx.x * 256 + threadIdx.x;  // 0..6143 float4s
  *(float4*)(csb + g * 4) = float4{0.f, 0.f, 0.f, 0.f};
  if (blockIdx.x == 0 && threadIdx.x < B) {
    int b = threadIdx.x;
    float NMf = (float)N * (float)M;
    float mean = stats[b * 4 + 0] / NMf;
    float var = stats[b * 4 + 1] / NMf - mean * mean;
    var = fmaxf(var, 0.0f);
    float stdv = sqrtf(var + EPS_IN);
    float s = in_w[0] / stdv;
    float t = in_b[0] - mean * s;
    float emax = __uint_as_float(((const unsigned int*)stats)[b * 4 + 2]);
    float Amax = fmaxf(fmaf(s, emax, t), t);
    float KK = fmaxf(Amax - 60.0f, 0.0f);
    params[b * 8 + 0] = s * LOG2E;
    params[b * 8 + 1] = (t - 2.0f * KK) * LOG2E;
    params[b * 8 + 2] = KK;
    params[b * 8 + 3] = __expf(-KK);
    params[b * 8 + 4] = __expf(KK);
  }
}

// ---------------------------------------------------------------------------
// Kernel 5: fused sinkhorn iteration (round-9-proven: 8 rows/block, 2 rows
// per wave, 1024 blocks).  PASS1 keeps p in named float4 registers, PASS2 is
// full-rate fma(p,g,acc).  All 8 e-loads issued before the prologue so
// HBM/L3 latency hides under the C2 log computation.  Epilogue atomics
// wave-coalesced (round-7-proven).
// ---------------------------------------------------------------------------
#define PASS1(uu, off, PA, PB)                           \
  {                                                      \
    float4 ca = *(const float4*)&C2a[(off) + ln4];       \
    float4 cb = *(const float4*)&C2b[(off) + ln4];       \
    PA.x = fexp2(fmaf(blo(uu.x), sL, ca.x));             \
    PA.y = fexp2(fmaf(bhi(uu.x), sL, ca.y));             \
    PA.z = fexp2(fmaf(blo(uu.y), sL, ca.z));             \
    PA.w = fexp2(fmaf(bhi(uu.y), sL, ca.w));             \
    PB.x = fexp2(fmaf(blo(uu.z), sL, cb.x));             \
    PB.y = fexp2(fmaf(bhi(uu.z), sL, cb.y));             \
    PB.z = fexp2(fmaf(blo(uu.w), sL, cb.z));             \
    PB.w = fexp2(fmaf(bhi(uu.w), sL, cb.w));             \
    s0 += PA.x + PB.x;                                   \
    s1 += PA.y + PB.y;                                   \
    s2 += PA.z + PB.z;                                   \
    s3 += PA.w + PB.w;                                   \
  }

#define PASS2(PA, PB, AA, BB)                            \
  {                                                      \
    AA.x = fmaf(PA.x, g, AA.x);                          \
    AA.y = fmaf(PA.y, g, AA.y);                          \
    AA.z = fmaf(PA.z, g, AA.z);                          \
    AA.w = fmaf(PA.w, g, AA.w);                          \
    BB.x = fmaf(PB.x, g, BB.x);                          \
    BB.y = fmaf(PB.y, g, BB.y);                          \
    BB.z = fmaf(PB.z, g, BB.z);                          \
    BB.w = fmaf(PB.w, g, BB.w);                          \
  }

__global__ __launch_bounds__(256) void sink_pass(
    const ushort_t* __restrict__ e, const float* __restrict__ params,
    const float* __restrict__ cs_cur, float* __restrict__ cs_nxt,
    float* __restrict__ cs_zz, float* __restrict__ R) {
  __shared__ __align__(16) float C2a[1024], C2b[1024];
  __shared__ __align__(16) float Ds[2048];
  __shared__ __align__(16) float colA[1024], colB[1024];
  int t = threadIdx.x;
  int b = blockIdx.y, blk = blockIdx.x;  // blk 0..255
  int w = t >> 6, lane = t & 63;
  int ln4 = lane * 4;
  const float* pr = params + b * 8;
  float sL = pr[0], c0L = pr[1], KK = pr[2], enk = pr[3], ekk = pr[4];

  // issue both rows' e-loads FIRST: latency hides under the prologue
  int r0 = blk * 8 + w * 2;
  const ushort_t* ep = e + (size_t)(b * N + r0) * M + lane * 8;
  uint4 u0 = *(const uint4*)(ep);
  uint4 u1 = *(const uint4*)(ep + 512);
  uint4 u2 = *(const uint4*)(ep + 1024);
  uint4 u3 = *(const uint4*)(ep + 1536);
  const ushort_t* ep2 = ep + M;
  uint4 v0 = *(const uint4*)(ep2);
  uint4 v1 = *(const uint4*)(ep2 + 512);
  uint4 v2 = *(const uint4*)(ep2 + 1024);
  uint4 v3 = *(const uint4*)(ep2 + 1536);

  if (blk == 0) {  // coalesced zero of next iteration's accumulator
#pragma unroll
    for (int k = 0; k < 2; k++)
      *(float4*)(cs_zz + b * M + (k * 256 + t) * 4) = float4{0.f, 0.f, 0.f, 0.f};
  }
  {  // prologue: thread t owns columns [t*8, t*8+8)
    float4 c0 = *(const float4*)(cs_cur + b * M + t * 8);
    float4 c1 = *(const float4*)(cs_cur + b * M + t * 8 + 4);
    c0.x += enk; c0.y += enk; c0.z += enk; c0.w += enk;
    c1.x += enk; c1.y += enk; c1.z += enk; c1.w += enk;
    float4 ca, cb;
    ca.x = c0L - flog2(c0.x); ca.y = c0L - flog2(c0.y);
    ca.z = c0L - flog2(c0.z); ca.w = c0L - flog2(c0.w);
    cb.x = c0L - flog2(c1.x); cb.y = c0L - flog2(c1.y);
    cb.z = c0L - flog2(c1.z); cb.w = c0L - flog2(c1.w);
    *(float4*)&C2a[w * 256 + ln4] = ca;
    *(float4*)&C2b[w * 256 + ln4] = cb;
    float4 d0 = {ekk * c0.x, ekk * c0.y, ekk * c0.z, ekk * c0.w};
    float4 d1 = {ekk * c1.x, ekk * c1.y, ekk * c1.z, ekk * c1.w};
    *(float4*)&Ds[t * 8] = d0;  // Ds is plain column-indexed
    *(float4*)&Ds[t * 8 + 4] = d1;
  }
  __syncthreads();

  float4 accA0 = {0,0,0,0}, accA1 = {0,0,0,0}, accA2 = {0,0,0,0}, accA3 = {0,0,0,0};
  float4 accB0 = {0,0,0,0}, accB1 = {0,0,0,0}, accB2 = {0,0,0,0}, accB3 = {0,0,0,0};
  float4 pA0, pA1, pA2, pA3, pB0, pB1, pB2, pB3;

  // ---- row 0 ----
  {
    float s0 = 0, s1 = 0, s2 = 0, s3 = 0;
    PASS1(u0, 0, pA0, pB0)
    PASS1(u1, 256, pA1, pB1)
    PASS1(u2, 512, pA2, pB2)
    PASS1(u3, 768, pA3, pB3)
    float sum = (s0 + s1) + (s2 + s3);
#pragma unroll
    for (int off = 32; off; off >>= 1) sum += __shfl_xor(sum, off, 64);
    float sumtot = sum + enk;
    float ls = flog2(sumtot);
    if (lane == 0) R[b * N + r0] = KK + LN2 * ls;
    float g = fexp2(-KK * LOG2E - ls);  // g = enk/sumtot
    PASS2(pA0, pB0, accA0, accB0)
    PASS2(pA1, pB1, accA1, accB1)
    PASS2(pA2, pB2, accA2, accB2)
    PASS2(pA3, pB3, accA3, accB3)
  }
  // ---- row 1 ----
  {
    float s0 = 0, s1 = 0, s2 = 0, s3 = 0;
    PASS1(v0, 0, pA0, pB0)
    PASS1(v1, 256, pA1, pB1)
    PASS1(v2, 512, pA2, pB2)
    PASS1(v3, 768, pA3, pB3)
    float sum = (s0 + s1) + (s2 + s3);
#pragma unroll
    for (int off = 32; off; off >>= 1) sum += __shfl_xor(sum, off, 64);
    float sumtot = sum + enk;
    float ls = flog2(sumtot);
    if (lane == 0) R[b * N + r0 + 1] = KK + LN2 * ls;
    float g = fexp2(-KK * LOG2E - ls);
    PASS2(pA0, pB0, accA0, accB0)
    PASS2(pA1, pB1, accA1, accB1)
    PASS2(pA2, pB2, accA2, accB2)
    PASS2(pA3, pB3, accA3, accB3)
  }

  // combine the 4 waves' column partials in LDS (permuted layout)
  for (int ww = 0; ww < 4; ww++) {
    if (w == ww) {
      if (ww == 0) {
        *(float4*)&colA[ln4] = accA0;
        *(float4*)&colA[256 + ln4] = accA1;
        *(float4*)&colA[512 + ln4] = accA2;
        *(float4*)&colA[768 + ln4] = accA3;
        *(float4*)&colB[ln4] = accB0;
        *(float4*)&colB[256 + ln4] = accB1;
        *(float4*)&colB[512 + ln4] = accB2;
        *(float4*)&colB[768 + ln4] = accB3;
      } else {
        float4 q;
        q = *(float4*)&colA[ln4];
        q.x += accA0.x; q.y += accA0.y; q.z += accA0.z; q.w += accA0.w;
        *(float4*)&colA[ln4] = q;
        q = *(float4*)&colA[256 + ln4];
        q.x += accA1.x; q.y += accA1.y; q.z += accA1.z; q.w += accA1.w;
        *(float4*)&colA[256 + ln4] = q;
        q = *(float4*)&colA[512 + ln4];
        q.x += accA2.x; q.y += accA2.y; q.z += accA2.z; q.w += accA2.w;
        *(float4*)&colA[512 + ln4] = q;
        q = *(float4*)&colA[768 + ln4];
        q.x += accA3.x; q.y += accA3.y; q.z += accA3.z; q.w += accA3.w;
        *(float4*)&colA[768 + ln4] = q;
        q = *(float4*)&colB[ln4];
        q.x += accB0.x; q.y += accB0.y; q.z += accB0.z; q.w += accB0.w;
        *(float4*)&colB[ln4] = q;
        q = *(float4*)&colB[256 + ln4];
        q.x += accB1.x; q.y += accB1.y; q.z += accB1.z; q.w += accB1.w;
        *(float4*)&colB[256 + ln4] = q;
        q = *(float4*)&colB[512 + ln4];
        q.x += accB2.x; q.y += accB2.y; q.z += accB2.z; q.w += accB2.w;
        *(float4*)&colB[512 + ln4] = q;
        q = *(float4*)&colB[768 + ln4];
        q.x += accB3.x; q.y += accB3.y; q.z += accB3.z; q.w += accB3.w;
        *(float4*)&colB[768 + ln4] = q;
      }
    }
    __syncthreads();
  }
  {  // epilogue: WAVE-COALESCED atomics; thread t owns columns {k*256+t}.
    int q = t & 7;
    const float* srcb = (q < 4) ? colA : colB;
    int qq = q & 3;
#pragma unroll
    for (int k = 0; k < 8; k++) {
      int j = k * 256 + t;
      int idx = (j >> 9) * 256 + ((j >> 3) & 63) * 4 + qq;
      atomicAdd(&cs_nxt[b * M + j], srcb[idx] * Ds[j]);
    }
  }
}

// ---------------------------------------------------------------------------
// Kernel 7: aw[i] = exp2(max_j fma(e,sL,C2L_j) + (KK - R_i)*log2e).
// ---------------------------------------------------------------------------
__global__ __launch_bounds__(256) void awmax_kernel(
    const ushort_t* __restrict__ e, const float* __restrict__ params,
    const float* __restrict__ cs_fin, const float* __restrict__ R,
    float* __restrict__ aw) {
  __shared__ __align__(16) float C2a[1024], C2b[1024];
  int t = threadIdx.x;
  int b = blockIdx.y, blk = blockIdx.x;
  const float* pr = params + b * 8;
  float sL = pr[0], c0L = pr[1], KK = pr[2], enk = pr[3];
  {
    float4 v0 = *(const float4*)(cs_fin + b * M + t * 8);
    float4 v1 = *(const float4*)(cs_fin + b * M + t * 8 + 4);
    float4 ca, cb;
    ca.x = c0L - flog2(v0.x + enk); ca.y = c0L - flog2(v0.y + enk);
    ca.z = c0L - flog2(v0.z + enk); ca.w = c0L - flog2(v0.w + enk);
    cb.x = c0L - flog2(v1.x + enk); cb.y = c0L - flog2(v1.y + enk);
    cb.z = c0L - flog2(v1.z + enk); cb.w = c0L - flog2(v1.w + enk);
    int it = t >> 6, ln = t & 63;
    *(float4*)&C2a[it * 256 + ln * 4] = ca;
    *(float4*)&C2b[it * 256 + ln * 4] = cb;
  }
  __syncthreads();

  int w = t >> 6, lane = t & 63;
  int ln4 = lane * 4;
  int r0 = blk * 16 + w * 4;
  const ushort_t* erow = e + (size_t)(b * N + r0) * M;
#pragma unroll
  for (int rr = 0; rr < 4; rr++) {
    float mx = -3.4e38f;
#pragma unroll
    for (int it = 0; it < 4; it++) {
      uint4 u = *(const uint4*)(erow + (size_t)rr * M + it * 512 + lane * 8);
      float4 ca = *(const float4*)&C2a[it * 256 + ln4];
      float4 cb = *(const float4*)&C2b[it * 256 + ln4];
      mx = fmaxf(mx, fmaf(blo(u.x), sL, ca.x));
      mx = fmaxf(mx, fmaf(bhi(u.x), sL, ca.y));
      mx = fmaxf(mx, fmaf(blo(u.y), sL, ca.z));
      mx = fmaxf(mx, fmaf(bhi(u.y), sL, ca.w));
      mx = fmaxf(mx, fmaf(blo(u.z), sL, cb.x));
      mx = fmaxf(mx, fmaf(bhi(u.z), sL, cb.y));
      mx = fmaxf(mx, fmaf(blo(u.w), sL, cb.z));
      mx = fmaxf(mx, fmaf(bhi(u.w), sL, cb.w));
    }
#pragma unroll
    for (int off = 32; off; off >>= 1) mx = fmaxf(mx, __shfl_xor(mx, off, 64));
    if (lane == 0) {
      float Rr = R[b * N + r0 + rr];
      aw[b * N + r0 + rr] = fexp2(mx + (KK - Rr) * LOG2E);
    }
  }
}

// ---------------------------------------------------------------------------
// Kernel 8: out[b,n,m] = aw[b,n] * aw[b,m], float4 stores.
// ---------------------------------------------------------------------------
__global__ __launch_bounds__(256) void outer_kernel(const float* __restrict__ aw,
                                                    float* __restrict__ out) {
  size_t idx = (size_t)blockIdx.x * 256 + threadIdx.x;
  int b = (int)(idx >> 20);
  size_t rem = idx & ((1u << 20) - 1);
  int n = (int)(rem >> 9);
  int m4 = (int)(rem & 511) << 2;
  float a = aw[b * N + n];
  float4 wv = *(const float4*)(aw + b * N + m4);
  float4 o = {a * wv.x, a * wv.y, a * wv.z, a * wv.w};
  *(float4*)(out + (idx << 2)) = o;
}

// ---------------------------------------------------------------------------
extern "C" void kernel_launch(void* const* d_in, const int* in_sizes, int n_in,
                              void* d_out, int out_size, void* d_ws, size_t ws_size,
                              hipStream_t stream) {
  const float* x = (const float*)d_in[0];
  const float* y = (const float*)d_in[1];
  const float* Wq = (const float*)d_in[2];
  const float* bq = (const float*)d_in[3];
  const float* in_w = (const float*)d_in[4];
  const float* in_b = (const float*)d_in[5];
  ushort_t* e = (ushort_t*)d_out;  // 33.5 MB bf16 scratch; overwritten by outer

  float* ws = (float*)d_ws;
  ushort_t* qwh = (ushort_t*)ws;     // 16384*64 bf16 = 524288 f32-slots
  float* norms = ws + 1048576;       // 16384 (offset kept from prior layout)
  float* R = norms + 16384;          // 8192
  float* csb0 = R + 8192;            // 8192
  float* csb1 = csb0 + 8192;         // 8192
  float* csb2 = csb1 + 8192;         // 8192
  float* aw = csb2 + 8192;           // 8192
  float* stats = aw + 8192;          // 32
  float* params = stats + 32;        // 32
  float* csb[3] = {csb0, csb1, csb2};

  proj_kernel<<<512, 256, 0, stream>>>(x, y, Wq, bq, qwh, norms, stats);
  dist_kernel<<<dim3(16, 16, B), 256, 0, stream>>>(qwh, norms, e, stats);
  params_csinit_kernel<<<24, 256, 0, stream>>>(stats, in_w, in_b, params, csb0);

  for (int it = 0; it < ITERS; it++) {
    sink_pass<<<dim3(256, B), 256, 0, stream>>>(
        e, params, csb[it % 3], csb[(it + 1) % 3], csb[(it + 2) % 3], R);
  }
  awmax_kernel<<<dim3(128, B), 256, 0, stream>>>(e, params, csb[ITERS % 3], R, aw);
  outer_kernel<<<16384, 256, 0, stream>>>(aw, (float*)d_out);
}